// Round 1
// baseline (1317.857 us; speedup 1.0000x reference)
//
#include <hip/hip_runtime.h>
#include <hip/hip_bf16.h>
#include <cstdint>

// ---------------------------------------------------------------------------
// Model: h=relu(x@W1+b1); h=AGNN(h,beta=1); h=AGNN(h,beta2); h=relu(h@W2+b2);
//        out = concat(segmax(h,batch), segmean(h,batch)) @ W3 + b3
// N=30000, E=480000, F_IN=1280, H=512, H2=256, G=64, C=10
// ---------------------------------------------------------------------------

typedef __attribute__((ext_vector_type(8))) short bf16x8;
typedef __attribute__((ext_vector_type(4))) float f32x4;
typedef __attribute__((ext_vector_type(8))) unsigned short ushort8;

__device__ inline unsigned short f2bf(float f) {
    unsigned int u = __float_as_uint(f);
    u += 0x7FFFu + ((u >> 16) & 1u);   // round-to-nearest-even
    return (unsigned short)(u >> 16);
}

// ---- f32 -> bf16 flat convert (n multiple of 8) ---------------------------
__global__ void k_cvt_bf16(const float* __restrict__ in,
                           unsigned short* __restrict__ out, long n) {
    long i = ((long)blockIdx.x * blockDim.x + threadIdx.x) * 8;
    if (i >= n) return;
    float4 a = *(const float4*)(in + i);
    float4 b = *(const float4*)(in + i + 4);
    ushort8 r;
    r[0] = f2bf(a.x); r[1] = f2bf(a.y); r[2] = f2bf(a.z); r[3] = f2bf(a.w);
    r[4] = f2bf(b.x); r[5] = f2bf(b.y); r[6] = f2bf(b.z); r[7] = f2bf(b.w);
    *(ushort8*)(out + i) = r;
}

// ---- W [K][N] f32  ->  Wt [N][K] bf16 -------------------------------------
__global__ void k_transpose_bf16(const float* __restrict__ W,
                                 unsigned short* __restrict__ Wt, int K, int N) {
    long idx = (long)blockIdx.x * blockDim.x + threadIdx.x;
    long total = (long)K * N;
    if (idx >= total) return;
    int nn = (int)(idx / K);
    int kk = (int)(idx % K);
    Wt[idx] = f2bf(W[(long)kk * N + nn]);
}

// ---- MFMA GEMM: C[M][N] = relu(A[M][K] * Bt[N][K]^T + bias) ---------------
// block = 256 threads = 4 waves, wave grid 2(M) x 2(N); wave tile 16x64.
// Block tile 32 x 128.
template <int K, int N>
__global__ __launch_bounds__(256) void k_gemm_bias_relu(
    const unsigned short* __restrict__ A, const unsigned short* __restrict__ Bt,
    const float* __restrict__ bias, float* __restrict__ C, int M) {
    int tid = threadIdx.x;
    int w = tid >> 6, l = tid & 63;
    int wm = w >> 1, wn = w & 1;
    int mBase = blockIdx.x * 32 + wm * 16;
    int nBase = blockIdx.y * 128 + wn * 64;
    int ra = mBase + (l & 15);
    int kk = (l >> 4) * 8;
    bool aok = ra < M;
    const unsigned short* ap = A + (long)ra * K + kk;
    const unsigned short* bp[4];
#pragma unroll
    for (int j = 0; j < 4; j++)
        bp[j] = Bt + (long)(nBase + j * 16 + (l & 15)) * K + kk;

    f32x4 acc[4] = {{0.f, 0.f, 0.f, 0.f}, {0.f, 0.f, 0.f, 0.f},
                    {0.f, 0.f, 0.f, 0.f}, {0.f, 0.f, 0.f, 0.f}};
    for (int k0 = 0; k0 < K; k0 += 32) {
        bf16x8 a = {};
        if (aok) a = *(const bf16x8*)(ap);
        ap += 32;
#pragma unroll
        for (int j = 0; j < 4; j++) {
            bf16x8 b = *(const bf16x8*)(bp[j]);
            bp[j] += 32;
            acc[j] = __builtin_amdgcn_mfma_f32_16x16x32_bf16(a, b, acc[j], 0, 0, 0);
        }
    }
    // epilogue: C row = (l>>4)*4 + r, col = lane&15  (verified gfx950 layout)
#pragma unroll
    for (int j = 0; j < 4; j++) {
        int col = nBase + j * 16 + (l & 15);
        float bv = bias[col];
#pragma unroll
        for (int r = 0; r < 4; r++) {
            int rowc = mBase + (l >> 4) * 4 + r;
            if (rowc < M) {
                float v = acc[j][r] + bv;
                C[(long)rowc * N + col] = fmaxf(v, 0.f);
            }
        }
    }
}

// ---- CSR build ------------------------------------------------------------
__global__ void k_csr_init(int* __restrict__ cnt, int* __restrict__ fill, int n) {
    int i = blockIdx.x * blockDim.x + threadIdx.x;
    if (i < n) { cnt[i] = 1; fill[i] = 0; }   // 1 = self loop
}

__global__ void k_csr_count(const int* __restrict__ ei, int* __restrict__ cnt, int E) {
    int e = blockIdx.x * blockDim.x + threadIdx.x;
    if (e < E) atomicAdd(&cnt[ei[E + e]], 1);   // dst row
}

__global__ void k_csr_scan(const int* __restrict__ cnt, int* __restrict__ rowp, int n) {
    __shared__ int buf[1024];
    __shared__ int carry_s;
    int t = threadIdx.x;
    if (t == 0) carry_s = 0;
    __syncthreads();
    for (int base = 0; base < n; base += 1024) {
        int v = (base + t < n) ? cnt[base + t] : 0;
        buf[t] = v;
        __syncthreads();
        for (int off = 1; off < 1024; off <<= 1) {
            int x = (t >= off) ? buf[t - off] : 0;
            __syncthreads();
            buf[t] += x;
            __syncthreads();
        }
        int incl = buf[t];
        if (base + t < n) rowp[base + t] = carry_s + incl - v;
        __syncthreads();
        if (t == 1023) carry_s += incl;
        __syncthreads();
    }
    if (t == 0) rowp[n] = carry_s;
}

__global__ void k_csr_fill(const int* __restrict__ ei, const int* __restrict__ rowp,
                           int* __restrict__ fill, int* __restrict__ col, int E, int n) {
    int idx = blockIdx.x * blockDim.x + threadIdx.x;
    if (idx < E) {
        int d = ei[E + idx];
        int s = ei[idx];
        int pos = atomicAdd(&fill[d], 1);
        col[rowp[d] + pos] = s;
    } else if (idx < E + n) {
        int nd = idx - E;
        int pos = atomicAdd(&fill[nd], 1);
        col[rowp[nd] + pos] = nd;   // self loop
    }
}

// ---- row inverse L2 norm (H=512) ------------------------------------------
__global__ __launch_bounds__(256) void k_norm(const float* __restrict__ h,
                                              float* __restrict__ invn, int n) {
    int row = blockIdx.x * 4 + (threadIdx.x >> 6);
    int lane = threadIdx.x & 63;
    if (row >= n) return;
    const float* r = h + (long)row * 512;
    float4 a = *(const float4*)(r + lane * 4);
    float4 b = *(const float4*)(r + 256 + lane * 4);
    float s = a.x * a.x + a.y * a.y + a.z * a.z + a.w * a.w +
              b.x * b.x + b.y * b.y + b.z * b.z + b.w * b.w;
#pragma unroll
    for (int off = 32; off; off >>= 1) s += __shfl_xor(s, off, 64);
    if (lane == 0) invn[row] = 1.f / fmaxf(sqrtf(s), 1e-12f);
}

// ---- AGNN propagation, dst-centric, one wave per dst (H=512) --------------
__global__ __launch_bounds__(256) void k_agnn(
    const float* __restrict__ h, const float* __restrict__ invn,
    const int* __restrict__ rowp, const int* __restrict__ col,
    const float* __restrict__ beta_ptr, float* __restrict__ out, int nNodes) {
    int dst = blockIdx.x * 4 + (threadIdx.x >> 6);
    int lane = threadIdx.x & 63;
    if (dst >= nNodes) return;
    float beta = beta_ptr ? beta_ptr[0] : 1.0f;
    const float* hr = h + (long)dst * 512;
    float4 hd0 = *(const float4*)(hr + lane * 4);
    float4 hd1 = *(const float4*)(hr + 256 + lane * 4);
    float ind = invn[dst];
    int s0 = rowp[dst], s1 = rowp[dst + 1];

    // pass A: online softmax stats (m, sum)
    float m = -1e30f, ssum = 0.f;
    for (int i = s0; i < s1; i++) {
        int src = col[i];
        const float* sr = h + (long)src * 512;
        float4 a0 = *(const float4*)(sr + lane * 4);
        float4 a1 = *(const float4*)(sr + 256 + lane * 4);
        float p = a0.x * hd0.x + a0.y * hd0.y + a0.z * hd0.z + a0.w * hd0.w +
                  a1.x * hd1.x + a1.y * hd1.y + a1.z * hd1.z + a1.w * hd1.w;
#pragma unroll
        for (int off = 32; off; off >>= 1) p += __shfl_xor(p, off, 64);
        float alpha = beta * ind * invn[src] * p;
        float nm = fmaxf(m, alpha);
        ssum = ssum * __expf(m - nm) + __expf(alpha - nm);
        m = nm;
    }
    float inv_s = 1.f / ssum;

    // pass B: weighted accumulate of raw source rows
    float4 acc0 = {0.f, 0.f, 0.f, 0.f}, acc1 = {0.f, 0.f, 0.f, 0.f};
    for (int i = s0; i < s1; i++) {
        int src = col[i];
        const float* sr = h + (long)src * 512;
        float4 a0 = *(const float4*)(sr + lane * 4);
        float4 a1 = *(const float4*)(sr + 256 + lane * 4);
        float p = a0.x * hd0.x + a0.y * hd0.y + a0.z * hd0.z + a0.w * hd0.w +
                  a1.x * hd1.x + a1.y * hd1.y + a1.z * hd1.z + a1.w * hd1.w;
#pragma unroll
        for (int off = 32; off; off >>= 1) p += __shfl_xor(p, off, 64);
        float alpha = beta * ind * invn[src] * p;
        float wgt = __expf(alpha - m) * inv_s;
        acc0.x += wgt * a0.x; acc0.y += wgt * a0.y;
        acc0.z += wgt * a0.z; acc0.w += wgt * a0.w;
        acc1.x += wgt * a1.x; acc1.y += wgt * a1.y;
        acc1.z += wgt * a1.z; acc1.w += wgt * a1.w;
    }
    float* op = out + (long)dst * 512;
    *(float4*)(op + lane * 4) = acc0;
    *(float4*)(op + 256 + lane * 4) = acc1;
}

// ---- graph boundaries in sorted batch -------------------------------------
__global__ void k_bounds(const int* __restrict__ batch, int* __restrict__ starts,
                         int n, int G) {
    int g = blockIdx.x * blockDim.x + threadIdx.x;
    if (g > G) return;
    int lo = 0, hi = n;
    while (lo < hi) {
        int mid = (lo + hi) >> 1;
        if (batch[mid] < g) lo = mid + 1; else hi = mid;
    }
    starts[g] = lo;
}

// ---- per-graph max/mean pool (H2=256) -------------------------------------
__global__ __launch_bounds__(256) void k_pool(const float* __restrict__ h3,
                                              const int* __restrict__ starts,
                                              float* __restrict__ pooled) {
    int g = blockIdx.x;
    int t = threadIdx.x;   // 256 = H2 dims
    int s = starts[g], e = starts[g + 1];
    float mx = -3.402823466e38f, sm = 0.f;
    for (int r = s; r < e; r++) {
        float v = h3[(long)r * 256 + t];
        mx = fmaxf(mx, v);
        sm += v;
    }
    float cnt = fmaxf((float)(e - s), 1.f);
    pooled[g * 512 + t] = mx;
    pooled[g * 512 + 256 + t] = sm / cnt;
}

// ---- final tiny GEMM: out[G][C] = pooled[G][512] @ W3[512][C] + b3 --------
__global__ __launch_bounds__(64) void k_final(const float* __restrict__ pooled,
                                              const float* __restrict__ W3,
                                              const float* __restrict__ b3,
                                              float* __restrict__ out, int C) {
    int g = blockIdx.x;
    int lane = threadIdx.x;
    for (int c = 0; c < C; c++) {
        float p = 0.f;
        for (int k = lane; k < 512; k += 64) p += pooled[g * 512 + k] * W3[k * C + c];
#pragma unroll
        for (int off = 32; off; off >>= 1) p += __shfl_xor(p, off, 64);
        if (lane == 0) out[g * C + c] = p + b3[c];
    }
}

// ---------------------------------------------------------------------------
extern "C" void kernel_launch(void* const* d_in, const int* in_sizes, int n_in,
                              void* d_out, int out_size, void* d_ws, size_t ws_size,
                              hipStream_t stream) {
    const float* x     = (const float*)d_in[0];
    const int*   ei    = (const int*)d_in[1];
    const int*   batch = (const int*)d_in[2];
    const float* W1    = (const float*)d_in[3];
    const float* b1    = (const float*)d_in[4];
    const float* beta2 = (const float*)d_in[5];
    const float* W2    = (const float*)d_in[6];
    const float* b2    = (const float*)d_in[7];
    const float* W3    = (const float*)d_in[8];
    const float* b3    = (const float*)d_in[9];
    float* out = (float*)d_out;

    const int N = in_sizes[2];          // 30000
    const int E = in_sizes[1] / 2;      // 480000
    const int F_IN = in_sizes[0] / N;   // 1280
    const int H = in_sizes[4];          // 512
    const int H2 = in_sizes[7];         // 256
    const int C = in_sizes[9];          // 10
    const int G = out_size / C;         // 64

    char* ws = (char*)d_ws;
    // region 0 (80 MB): x_bf16 -> prop1_out(f32) -> h2_bf16
    unsigned short* XB  = (unsigned short*)(ws + 0);
    float*          HP  = (float*)(ws + 0);
    unsigned short* H2B = (unsigned short*)(ws + 0);
    // region 1 (64 MB): h1(f32) -> prop2_out(f32) -> h3(f32)
    float* H1 = (float*)(ws + 80000000L);
    float* H3 = (float*)(ws + 80000000L);
    // aux region
    unsigned short* W1T   = (unsigned short*)(ws + 144000000L);   // 1.31 MB
    unsigned short* W2T   = (unsigned short*)(ws + 145400000L);   // 0.26 MB
    float*          INVN  = (float*)(ws + 145700000L);            // 120 KB
    int*            CNT   = (int*)(ws + 145830000L);              // 120 KB
    int*            FILL  = (int*)(ws + 145960000L);              // 120 KB
    int*            ROWP  = (int*)(ws + 146090000L);              // 120 KB
    int*            COL   = (int*)(ws + 146220000L);              // 2.04 MB
    int*            START = (int*)(ws + 148270000L);              // 260 B
    float*          POOLED= (float*)(ws + 148280000L);            // 131 KB

    // 1. conversions
    {
        long n = (long)N * F_IN;
        k_cvt_bf16<<<(int)((n / 8 + 255) / 256), 256, 0, stream>>>(x, XB, n);
    }
    k_transpose_bf16<<<(F_IN * H + 255) / 256, 256, 0, stream>>>(W1, W1T, F_IN, H);
    k_transpose_bf16<<<(H * H2 + 255) / 256, 256, 0, stream>>>(W2, W2T, H, H2);

    // 2. CSR (incoming edges + self loops)
    k_csr_init<<<(N + 255) / 256, 256, 0, stream>>>(CNT, FILL, N);
    k_csr_count<<<(E + 255) / 256, 256, 0, stream>>>(ei, CNT, E);
    k_csr_scan<<<1, 1024, 0, stream>>>(CNT, ROWP, N);
    k_csr_fill<<<(E + N + 255) / 256, 256, 0, stream>>>(ei, ROWP, FILL, COL, E, N);

    // 3. GEMM1: h1 = relu(x @ W1 + b1)   [N,512]
    {
        dim3 grid((N + 31) / 32, H / 128);
        k_gemm_bias_relu<1280, 512><<<grid, 256, 0, stream>>>(XB, W1T, b1, H1, N);
    }

    // 4. prop1 (beta = 1)
    k_norm<<<(N + 3) / 4, 256, 0, stream>>>(H1, INVN, N);
    k_agnn<<<(N + 3) / 4, 256, 0, stream>>>(H1, INVN, ROWP, COL, nullptr, HP, N);

    // 5. prop2 (beta = beta2)
    k_norm<<<(N + 3) / 4, 256, 0, stream>>>(HP, INVN, N);
    k_agnn<<<(N + 3) / 4, 256, 0, stream>>>(HP, INVN, ROWP, COL, beta2, H1, N);

    // 6. GEMM2: h3 = relu(prop2 @ W2 + b2)   [N,256]
    {
        long n = (long)N * H;
        k_cvt_bf16<<<(int)((n / 8 + 255) / 256), 256, 0, stream>>>(H1, H2B, n);
        dim3 grid((N + 31) / 32, H2 / 128);
        k_gemm_bias_relu<512, 256><<<grid, 256, 0, stream>>>(H2B, W2T, b2, H3, N);
    }

    // 7. pool + final linear
    k_bounds<<<1, 128, 0, stream>>>(batch, START, N, G);
    k_pool<<<G, 256, 0, stream>>>(H3, START, POOLED);
    k_final<<<G, 64, 0, stream>>>(POOLED, W3, b3, out, C);
}

// Round 2
// 699.317 us; speedup vs baseline: 1.8845x; 1.8845x over previous
//
#include <hip/hip_runtime.h>
#include <hip/hip_bf16.h>
#include <cstdint>

// ---------------------------------------------------------------------------
// Model: h=relu(x@W1+b1); h=AGNN(h,beta=1); h=AGNN(h,beta2); h=relu(h@W2+b2);
//        out = concat(segmax(h,batch), segmean(h,batch)) @ W3 + b3
// N=30000, E=480000, F_IN=1280, H=512, H2=256, G=64, C=10
// ---------------------------------------------------------------------------

typedef __attribute__((ext_vector_type(8))) short bf16x8;
typedef __attribute__((ext_vector_type(4))) float f32x4;
typedef __attribute__((ext_vector_type(8))) unsigned short ushort8;
typedef __attribute__((ext_vector_type(4))) unsigned short ushort4v;

__device__ inline unsigned short f2bf(float f) {
    unsigned int u = __float_as_uint(f);
    u += 0x7FFFu + ((u >> 16) & 1u);   // round-to-nearest-even
    return (unsigned short)(u >> 16);
}

__device__ __forceinline__ void gload_lds16(const void* g, void* l) {
    __builtin_amdgcn_global_load_lds(
        (const __attribute__((address_space(1))) void*)g,
        (__attribute__((address_space(3))) void*)l, 16, 0, 0);
}

// ---- f32 -> bf16 flat convert (n multiple of 8) ---------------------------
__global__ void k_cvt_bf16(const float* __restrict__ in,
                           unsigned short* __restrict__ out, long n) {
    long i = ((long)blockIdx.x * blockDim.x + threadIdx.x) * 8;
    if (i >= n) return;
    float4 a = *(const float4*)(in + i);
    float4 b = *(const float4*)(in + i + 4);
    ushort8 r;
    r[0] = f2bf(a.x); r[1] = f2bf(a.y); r[2] = f2bf(a.z); r[3] = f2bf(a.w);
    r[4] = f2bf(b.x); r[5] = f2bf(b.y); r[6] = f2bf(b.z); r[7] = f2bf(b.w);
    *(ushort8*)(out + i) = r;
}

// ---- W [K][N] f32  ->  Wt [N][K] bf16 -------------------------------------
__global__ void k_transpose_bf16(const float* __restrict__ W,
                                 unsigned short* __restrict__ Wt, int K, int N) {
    long idx = (long)blockIdx.x * blockDim.x + threadIdx.x;
    long total = (long)K * N;
    if (idx >= total) return;
    int nn = (int)(idx / K);
    int kk = (int)(idx % K);
    Wt[idx] = f2bf(W[(long)kk * N + nn]);
}

// ---- MFMA GEMM (m97 structure): C = relu(A[M][K] @ Bt[N][K]^T + bias) -----
// 256 threads = 4 waves (2x2), block tile 128x128, BK=32.
// LDS staging via global_load_lds width-16; 16 MFMA + 8 ds_read_b128 / K-step.
template <int K, int N>
__global__ __launch_bounds__(256) void k_gemm_bias_relu(
    const unsigned short* __restrict__ A, const unsigned short* __restrict__ Bt,
    const float* __restrict__ bias, float* __restrict__ C, int M) {
    __shared__ unsigned short As[128 * 32];
    __shared__ unsigned short Bs[128 * 32];
    int tid = threadIdx.x;
    int w = tid >> 6, l = tid & 63;
    int wm = w >> 1, wn = w & 1;
    int mBase = blockIdx.y * 128;
    int nBase = blockIdx.x * 128;

    f32x4 acc[4][4] = {};

    for (int k0 = 0; k0 < K; k0 += 32) {
        // ---- stage 128x32 A-tile and B-tile (each wave: 2 ops x 16 rows) --
#pragma unroll
        for (int o = 0; o < 2; ++o) {
            int rr = w * 32 + o * 16;           // tile-row base (wave-uniform)
            int lrow = rr + (l >> 2);           // this lane's tile row
            int kc = k0 + (l & 3) * 8;          // this lane's k column
            int gr = mBase + lrow; if (gr >= M) gr = M - 1;   // clamp tail
            gload_lds16(A + (long)gr * K + kc, As + rr * 32);
            gload_lds16(Bt + (long)(nBase + lrow) * K + kc, Bs + rr * 32);
        }
        __syncthreads();   // drains vmcnt -> tiles visible to all waves

        bf16x8 af[4], bfr[4];
#pragma unroll
        for (int m = 0; m < 4; ++m)
            af[m] = *(const bf16x8*)(As + (wm * 64 + m * 16 + (l & 15)) * 32 + (l >> 4) * 8);
#pragma unroll
        for (int n = 0; n < 4; ++n)
            bfr[n] = *(const bf16x8*)(Bs + (wn * 64 + n * 16 + (l & 15)) * 32 + (l >> 4) * 8);
#pragma unroll
        for (int m = 0; m < 4; ++m)
#pragma unroll
            for (int n = 0; n < 4; ++n)
                acc[m][n] = __builtin_amdgcn_mfma_f32_16x16x32_bf16(
                    af[m], bfr[n], acc[m][n], 0, 0, 0);
        __syncthreads();   // all waves done reading before next stage
    }

    // epilogue: row=(l>>4)*4+r, col=l&15 (verified on HW round 1)
#pragma unroll
    for (int m = 0; m < 4; ++m) {
        int row = mBase + wm * 64 + m * 16 + (l >> 4) * 4;
#pragma unroll
        for (int n = 0; n < 4; ++n) {
            int colg = nBase + wn * 64 + n * 16 + (l & 15);
            float bv = bias[colg];
#pragma unroll
            for (int r = 0; r < 4; ++r) {
                if (row + r < M)
                    C[(long)(row + r) * N + colg] = fmaxf(acc[m][n][r] + bv, 0.f);
            }
        }
    }
}

// ---- CSR build ------------------------------------------------------------
__global__ void k_csr_init(int* __restrict__ cnt, int* __restrict__ fill, int n) {
    int i = blockIdx.x * blockDim.x + threadIdx.x;
    if (i < n) { cnt[i] = 1; fill[i] = 0; }   // 1 = self loop
}

__global__ void k_csr_count(const int* __restrict__ ei, int* __restrict__ cnt, int E) {
    int e = blockIdx.x * blockDim.x + threadIdx.x;
    if (e < E) atomicAdd(&cnt[ei[E + e]], 1);   // dst row
}

__global__ __launch_bounds__(1024) void k_csr_scan(const int* __restrict__ cnt,
                                                   int* __restrict__ rowp, int n) {
    __shared__ int wsum[16];
    __shared__ int carry_s;
    int t = threadIdx.x, lane = t & 63, w = t >> 6;
    if (t == 0) carry_s = 0;
    __syncthreads();
    for (int base = 0; base < n; base += 1024) {
        int i = base + t;
        int v = (i < n) ? cnt[i] : 0;
        int x = v;   // inclusive wave scan
#pragma unroll
        for (int off = 1; off < 64; off <<= 1) {
            int y = __shfl_up(x, off, 64);
            if (lane >= off) x += y;
        }
        if (lane == 63) wsum[w] = x;
        __syncthreads();
        if (w == 0 && lane < 16) {
            int s = wsum[lane];
#pragma unroll
            for (int off = 1; off < 16; off <<= 1) {
                int y = __shfl_up(s, off, 64);
                if (lane >= off) s += y;
            }
            wsum[lane] = s;
        }
        __syncthreads();
        int waveOff = (w == 0) ? 0 : wsum[w - 1];
        if (i < n) rowp[i] = carry_s + waveOff + x - v;   // exclusive
        int total = wsum[15];
        __syncthreads();
        if (t == 0) carry_s += total;
        __syncthreads();
    }
    if (t == 0) rowp[n] = carry_s;
}

__global__ void k_csr_fill(const int* __restrict__ ei, const int* __restrict__ rowp,
                           int* __restrict__ fill, int* __restrict__ col, int E, int n) {
    int idx = blockIdx.x * blockDim.x + threadIdx.x;
    if (idx < E) {
        int d = ei[E + idx];
        int s = ei[idx];
        int pos = atomicAdd(&fill[d], 1);
        col[rowp[d] + pos] = s;
    } else if (idx < E + n) {
        int nd = idx - E;
        int pos = atomicAdd(&fill[nd], 1);
        col[rowp[nd] + pos] = nd;   // self loop
    }
}

// ---- row inverse L2 norm (H=512) ------------------------------------------
__global__ __launch_bounds__(256) void k_norm(const float* __restrict__ h,
                                              float* __restrict__ invn, int n) {
    int row = blockIdx.x * 4 + (threadIdx.x >> 6);
    int lane = threadIdx.x & 63;
    if (row >= n) return;
    const float* r = h + (long)row * 512;
    float4 a = *(const float4*)(r + lane * 4);
    float4 b = *(const float4*)(r + 256 + lane * 4);
    float s = a.x * a.x + a.y * a.y + a.z * a.z + a.w * a.w +
              b.x * b.x + b.y * b.y + b.z * b.z + b.w * b.w;
#pragma unroll
    for (int off = 32; off; off >>= 1) s += __shfl_xor(s, off, 64);
    if (lane == 0) invn[row] = 1.f / fmaxf(sqrtf(s), 1e-12f);
}

// ---- AGNN propagation, single-pass flash-style, one wave per dst ----------
template <bool OUTBF16>
__global__ __launch_bounds__(256) void k_agnn(
    const float* __restrict__ h, const float* __restrict__ invn,
    const int* __restrict__ rowp, const int* __restrict__ col,
    const float* __restrict__ beta_ptr, void* __restrict__ out, int nNodes) {
    int dst = blockIdx.x * 4 + (threadIdx.x >> 6);
    int lane = threadIdx.x & 63;
    if (dst >= nNodes) return;
    float beta = beta_ptr ? beta_ptr[0] : 1.0f;
    const float* hr = h + (long)dst * 512;
    float4 hd0 = *(const float4*)(hr + lane * 4);
    float4 hd1 = *(const float4*)(hr + 256 + lane * 4);
    float coef = beta * invn[dst];   // fold beta * invn[dst] once
    int s0 = rowp[dst], s1 = rowp[dst + 1];

    float m = -1e30f, ssum = 0.f;
    float4 acc0 = {0.f, 0.f, 0.f, 0.f}, acc1 = {0.f, 0.f, 0.f, 0.f};
    for (int i = s0; i < s1; i++) {
        int src = col[i];
        const float* sr = h + (long)src * 512;
        float4 a0 = *(const float4*)(sr + lane * 4);
        float4 a1 = *(const float4*)(sr + 256 + lane * 4);
        float p = a0.x * hd0.x + a0.y * hd0.y + a0.z * hd0.z + a0.w * hd0.w +
                  a1.x * hd1.x + a1.y * hd1.y + a1.z * hd1.z + a1.w * hd1.w;
#pragma unroll
        for (int off = 32; off; off >>= 1) p += __shfl_xor(p, off, 64);
        float alpha = coef * invn[src] * p;
        if (alpha > m) {               // wave-uniform branch (p fully reduced)
            float sc = __expf(m - alpha);
            ssum *= sc;
            acc0.x *= sc; acc0.y *= sc; acc0.z *= sc; acc0.w *= sc;
            acc1.x *= sc; acc1.y *= sc; acc1.z *= sc; acc1.w *= sc;
            m = alpha;
        }
        float e = __expf(alpha - m);
        ssum += e;
        acc0.x += e * a0.x; acc0.y += e * a0.y;
        acc0.z += e * a0.z; acc0.w += e * a0.w;
        acc1.x += e * a1.x; acc1.y += e * a1.y;
        acc1.z += e * a1.z; acc1.w += e * a1.w;
    }
    float inv_s = 1.f / ssum;
    acc0.x *= inv_s; acc0.y *= inv_s; acc0.z *= inv_s; acc0.w *= inv_s;
    acc1.x *= inv_s; acc1.y *= inv_s; acc1.z *= inv_s; acc1.w *= inv_s;
    if constexpr (OUTBF16) {
        unsigned short* ob = (unsigned short*)out + (long)dst * 512;
        ushort4v r0, r1;
        r0[0] = f2bf(acc0.x); r0[1] = f2bf(acc0.y); r0[2] = f2bf(acc0.z); r0[3] = f2bf(acc0.w);
        r1[0] = f2bf(acc1.x); r1[1] = f2bf(acc1.y); r1[2] = f2bf(acc1.z); r1[3] = f2bf(acc1.w);
        *(ushort4v*)(ob + lane * 4) = r0;
        *(ushort4v*)(ob + 256 + lane * 4) = r1;
    } else {
        float* op = (float*)out + (long)dst * 512;
        *(float4*)(op + lane * 4) = acc0;
        *(float4*)(op + 256 + lane * 4) = acc1;
    }
}

// ---- graph boundaries in sorted batch -------------------------------------
__global__ void k_bounds(const int* __restrict__ batch, int* __restrict__ starts,
                         int n, int G) {
    int g = blockIdx.x * blockDim.x + threadIdx.x;
    if (g > G) return;
    int lo = 0, hi = n;
    while (lo < hi) {
        int mid = (lo + hi) >> 1;
        if (batch[mid] < g) lo = mid + 1; else hi = mid;
    }
    starts[g] = lo;
}

// ---- per-graph max/mean pool (H2=256) -------------------------------------
__global__ __launch_bounds__(256) void k_pool(const float* __restrict__ h3,
                                              const int* __restrict__ starts,
                                              float* __restrict__ pooled) {
    int g = blockIdx.x;
    int t = threadIdx.x;   // 256 = H2 dims
    int s = starts[g], e = starts[g + 1];
    float mx = -3.402823466e38f, sm = 0.f;
    for (int r = s; r < e; r++) {
        float v = h3[(long)r * 256 + t];
        mx = fmaxf(mx, v);
        sm += v;
    }
    float cnt = fmaxf((float)(e - s), 1.f);
    pooled[g * 512 + t] = mx;
    pooled[g * 512 + 256 + t] = sm / cnt;
}

// ---- final tiny GEMM: out[G][C] = pooled[G][512] @ W3[512][C] + b3 --------
__global__ __launch_bounds__(64) void k_final(const float* __restrict__ pooled,
                                              const float* __restrict__ W3,
                                              const float* __restrict__ b3,
                                              float* __restrict__ out, int C) {
    int g = blockIdx.x;
    int lane = threadIdx.x;
    for (int c = 0; c < C; c++) {
        float p = 0.f;
        for (int k = lane; k < 512; k += 64) p += pooled[g * 512 + k] * W3[k * C + c];
#pragma unroll
        for (int off = 32; off; off >>= 1) p += __shfl_xor(p, off, 64);
        if (lane == 0) out[g * C + c] = p + b3[c];
    }
}

// ---------------------------------------------------------------------------
extern "C" void kernel_launch(void* const* d_in, const int* in_sizes, int n_in,
                              void* d_out, int out_size, void* d_ws, size_t ws_size,
                              hipStream_t stream) {
    const float* x     = (const float*)d_in[0];
    const int*   ei    = (const int*)d_in[1];
    const int*   batch = (const int*)d_in[2];
    const float* W1    = (const float*)d_in[3];
    const float* b1    = (const float*)d_in[4];
    const float* beta2 = (const float*)d_in[5];
    const float* W2    = (const float*)d_in[6];
    const float* b2    = (const float*)d_in[7];
    const float* W3    = (const float*)d_in[8];
    const float* b3    = (const float*)d_in[9];
    float* out = (float*)d_out;

    const int N = in_sizes[2];          // 30000
    const int E = in_sizes[1] / 2;      // 480000
    const int F_IN = in_sizes[0] / N;   // 1280
    const int H = in_sizes[4];          // 512
    const int H2 = in_sizes[7];         // 256
    const int C = in_sizes[9];          // 10
    const int G = out_size / C;         // 64

    char* ws = (char*)d_ws;
    // region 0 (80 MB): x_bf16 -> prop1_out(f32) -> h3(f32)
    unsigned short* XB = (unsigned short*)(ws + 0);
    float*          HP = (float*)(ws + 0);
    float*          H3 = (float*)(ws + 0);
    // region 1 (64 MB): h1(f32) -> h2_bf16 (prop2 out)
    float*          H1  = (float*)(ws + 80000000L);
    unsigned short* H2B = (unsigned short*)(ws + 80000000L);
    // aux region
    unsigned short* W1T   = (unsigned short*)(ws + 144000000L);   // 1.31 MB
    unsigned short* W2T   = (unsigned short*)(ws + 145400000L);   // 0.26 MB
    float*          INVN  = (float*)(ws + 145700000L);            // 120 KB
    int*            CNT   = (int*)(ws + 145830000L);              // 120 KB
    int*            FILL  = (int*)(ws + 145960000L);              // 120 KB
    int*            ROWP  = (int*)(ws + 146090000L);              // 120 KB
    int*            COL   = (int*)(ws + 146220000L);              // 2.04 MB
    int*            START = (int*)(ws + 148270000L);              // 260 B
    float*          POOLED= (float*)(ws + 148280000L);            // 131 KB

    // 1. conversions
    {
        long n = (long)N * F_IN;
        k_cvt_bf16<<<(int)((n / 8 + 255) / 256), 256, 0, stream>>>(x, XB, n);
    }
    k_transpose_bf16<<<(F_IN * H + 255) / 256, 256, 0, stream>>>(W1, W1T, F_IN, H);
    k_transpose_bf16<<<(H * H2 + 255) / 256, 256, 0, stream>>>(W2, W2T, H, H2);

    // 2. CSR (incoming edges + self loops)
    k_csr_init<<<(N + 255) / 256, 256, 0, stream>>>(CNT, FILL, N);
    k_csr_count<<<(E + 255) / 256, 256, 0, stream>>>(ei, CNT, E);
    k_csr_scan<<<1, 1024, 0, stream>>>(CNT, ROWP, N);
    k_csr_fill<<<(E + N + 255) / 256, 256, 0, stream>>>(ei, ROWP, FILL, COL, E, N);

    // 3. GEMM1: h1 = relu(x @ W1 + b1)   [N,512]
    {
        dim3 grid(H / 128, (N + 127) / 128);   // n-tiles fastest for A reuse
        k_gemm_bias_relu<1280, 512><<<grid, 256, 0, stream>>>(XB, W1T, b1, H1, N);
    }

    // 4. prop1 (beta = 1): HP = AGNN(H1)
    k_norm<<<(N + 3) / 4, 256, 0, stream>>>(H1, INVN, N);
    k_agnn<false><<<(N + 3) / 4, 256, 0, stream>>>(H1, INVN, ROWP, COL, nullptr, HP, N);

    // 5. prop2 (beta = beta2): H2B(bf16) = AGNN(HP)
    k_norm<<<(N + 3) / 4, 256, 0, stream>>>(HP, INVN, N);
    k_agnn<true><<<(N + 3) / 4, 256, 0, stream>>>(HP, INVN, ROWP, COL, beta2, H2B, N);

    // 6. GEMM2: h3 = relu(h2 @ W2 + b2)   [N,256]
    {
        dim3 grid(H2 / 128, (N + 127) / 128);
        k_gemm_bias_relu<512, 256><<<grid, 256, 0, stream>>>(H2B, W2T, b2, H3, N);
    }

    // 7. pool + final linear
    k_bounds<<<1, 128, 0, stream>>>(batch, START, N, G);
    k_pool<<<G, 256, 0, stream>>>(H3, START, POOLED);
    k_final<<<G, 64, 0, stream>>>(POOLED, W3, b3, out, C);
}

// Round 3
// 440.146 us; speedup vs baseline: 2.9941x; 1.5888x over previous
//
#include <hip/hip_runtime.h>
#include <hip/hip_bf16.h>
#include <cstdint>

// ---------------------------------------------------------------------------
// Model: h=relu(x@W1+b1); h=AGNN(h,beta=1); h=AGNN(h,beta2); h=relu(h@W2+b2);
//        out = concat(segmax(h,batch), segmean(h,batch)) @ W3 + b3
// N=30000, E=480000, F_IN=1280, H=512, H2=256, G=64, C=10
// Feature rows kept in bf16 throughout the propagation phase (halves gather BW).
// ---------------------------------------------------------------------------

typedef __attribute__((ext_vector_type(8))) short bf16x8;
typedef __attribute__((ext_vector_type(4))) float f32x4;
typedef __attribute__((ext_vector_type(8))) unsigned short ushort8;
typedef __attribute__((ext_vector_type(4))) unsigned short ushort4v;
typedef __attribute__((ext_vector_type(4))) unsigned int uint4v;

__device__ inline unsigned short f2bf(float f) {
    unsigned int u = __float_as_uint(f);
    u += 0x7FFFu + ((u >> 16) & 1u);   // RNE
    return (unsigned short)(u >> 16);
}

__device__ __forceinline__ float bf2f(unsigned short u) {
    return __uint_as_float(((unsigned int)u) << 16);
}

// packed f32x2 -> bf16x2 (RNE), single HW instruction on gfx950
__device__ __forceinline__ unsigned int cvtpk(float lo, float hi) {
    unsigned int r;
    asm("v_cvt_pk_bf16_f32 %0, %1, %2" : "=v"(r) : "v"(lo), "v"(hi));
    return r;
}

__device__ __forceinline__ void gload_lds16(const void* g, void* l) {
    __builtin_amdgcn_global_load_lds(
        (const __attribute__((address_space(1))) void*)g,
        (__attribute__((address_space(3))) void*)l, 16, 0, 0);
}

// ---- tiled transpose: W [K][N] f32 -> Wt [N][K] bf16 (K,N multiples of 32) -
__global__ __launch_bounds__(256) void k_transpose_bf16(
    const float* __restrict__ W, unsigned short* __restrict__ Wt, int K, int N) {
    __shared__ unsigned short t[32][33];
    int k0 = blockIdx.x * 32, n0 = blockIdx.y * 32;
    int tr = threadIdx.x >> 3;          // 0..31
    int tc = (threadIdx.x & 7) * 4;     // 0,4,...,28
    float4 v = *(const float4*)(W + (long)(k0 + tr) * N + n0 + tc);
    t[tr][tc + 0] = f2bf(v.x); t[tr][tc + 1] = f2bf(v.y);
    t[tr][tc + 2] = f2bf(v.z); t[tr][tc + 3] = f2bf(v.w);
    __syncthreads();
    ushort4v o = { t[tc + 0][tr], t[tc + 1][tr], t[tc + 2][tr], t[tc + 3][tr] };
    *(ushort4v*)(Wt + (long)(n0 + tr) * K + k0 + tc) = o;
}

// ---- MFMA GEMM: C = relu(A[M][K] @ Bt[N][K]^T + bias) ---------------------
// 256 threads = 4 waves (2x2), block tile 128x128, BK=32, LDS staged.
// AF32: A is f32 in global, reg-staged + converted to bf16 during LDS write.
// OUTBF16: C written as bf16.
template <int K, int N, bool AF32, bool OUTBF16>
__global__ __launch_bounds__(256) void k_gemm_bias_relu(
    const void* __restrict__ Av, const unsigned short* __restrict__ Bt,
    const float* __restrict__ bias, void* __restrict__ Cv, int M) {
    __shared__ unsigned short As[128 * 32];
    __shared__ unsigned short Bs[128 * 32];
    int tid = threadIdx.x;
    int w = tid >> 6, l = tid & 63;
    int wm = w >> 1, wn = w & 1;
    int mBase = blockIdx.y * 128;
    int nBase = blockIdx.x * 128;

    const float* Af = (const float*)Av;
    const unsigned short* Ab = (const unsigned short*)Av;
    int arow = tid >> 1;                 // AF32 staging: 2 threads/row
    int acol = (tid & 1) * 16;
    long aRowG = mBase + arow; if (aRowG >= M) aRowG = M - 1;

    f32x4 acc[4][4] = {};

    for (int k0 = 0; k0 < K; k0 += 32) {
        // ---- B tile via global_load_lds (and A too when already bf16) ----
#pragma unroll
        for (int o = 0; o < 2; ++o) {
            int rr = w * 32 + o * 16;          // wave-uniform row base
            int lrow = rr + (l >> 2);
            int kc = k0 + (l & 3) * 8;
            gload_lds16(Bt + (long)(nBase + lrow) * K + kc, Bs + rr * 32);
            if constexpr (!AF32) {
                long gr = mBase + lrow; if (gr >= M) gr = M - 1;
                gload_lds16(Ab + gr * K + kc, As + rr * 32);
            }
        }
        if constexpr (AF32) {
            const float* src = Af + aRowG * K + k0 + acol;
            float4 f0 = *(const float4*)(src);
            float4 f1 = *(const float4*)(src + 4);
            float4 f2 = *(const float4*)(src + 8);
            float4 f3 = *(const float4*)(src + 12);
            uint4v p0 = { cvtpk(f0.x, f0.y), cvtpk(f0.z, f0.w),
                          cvtpk(f1.x, f1.y), cvtpk(f1.z, f1.w) };
            uint4v p1 = { cvtpk(f2.x, f2.y), cvtpk(f2.z, f2.w),
                          cvtpk(f3.x, f3.y), cvtpk(f3.z, f3.w) };
            *(uint4v*)(As + arow * 32 + acol) = p0;
            *(uint4v*)(As + arow * 32 + acol + 8) = p1;
        }
        __syncthreads();

        bf16x8 af[4], bfr[4];
#pragma unroll
        for (int m = 0; m < 4; ++m)
            af[m] = *(const bf16x8*)(As + (wm * 64 + m * 16 + (l & 15)) * 32 + (l >> 4) * 8);
#pragma unroll
        for (int n = 0; n < 4; ++n)
            bfr[n] = *(const bf16x8*)(Bs + (wn * 64 + n * 16 + (l & 15)) * 32 + (l >> 4) * 8);
#pragma unroll
        for (int m = 0; m < 4; ++m)
#pragma unroll
            for (int n = 0; n < 4; ++n)
                acc[m][n] = __builtin_amdgcn_mfma_f32_16x16x32_bf16(
                    af[m], bfr[n], acc[m][n], 0, 0, 0);
        __syncthreads();
    }

    // epilogue: row=(l>>4)*4+r, col=l&15 (HW-verified)
#pragma unroll
    for (int m = 0; m < 4; ++m) {
        int row = mBase + wm * 64 + m * 16 + (l >> 4) * 4;
#pragma unroll
        for (int n = 0; n < 4; ++n) {
            int colg = nBase + wn * 64 + n * 16 + (l & 15);
            float bv = bias[colg];
#pragma unroll
            for (int r = 0; r < 4; ++r) {
                if (row + r < M) {
                    float v = fmaxf(acc[m][n][r] + bv, 0.f);
                    if constexpr (OUTBF16)
                        ((unsigned short*)Cv)[(long)(row + r) * N + colg] = f2bf(v);
                    else
                        ((float*)Cv)[(long)(row + r) * N + colg] = v;
                }
            }
        }
    }
}

// ---- CSR build ------------------------------------------------------------
__global__ void k_csr_init(int* __restrict__ cnt, int* __restrict__ fill, int n) {
    int i = blockIdx.x * blockDim.x + threadIdx.x;
    if (i < n) { cnt[i] = 1; fill[i] = 0; }   // 1 = self loop
}

__global__ void k_csr_count(const int* __restrict__ ei, int* __restrict__ cnt, int E) {
    int e = blockIdx.x * blockDim.x + threadIdx.x;
    if (e < E) atomicAdd(&cnt[ei[E + e]], 1);   // dst row
}

// hierarchical exclusive scan: phase 1 (per-1024-chunk scan + chunk total)
__global__ __launch_bounds__(1024) void k_scan1(const int* __restrict__ cnt,
                                                int* __restrict__ rowp,
                                                int* __restrict__ bsum, int n) {
    __shared__ int wsum[16];
    int b = blockIdx.x, t = threadIdx.x, lane = t & 63, w = t >> 6;
    int i = b * 1024 + t;
    int v = (i < n) ? cnt[i] : 0;
    int x = v;
#pragma unroll
    for (int off = 1; off < 64; off <<= 1) {
        int y = __shfl_up(x, off, 64);
        if (lane >= off) x += y;
    }
    if (lane == 63) wsum[w] = x;
    __syncthreads();
    if (t < 16) {
        int s = wsum[t];
#pragma unroll
        for (int off = 1; off < 16; off <<= 1) {
            int y = __shfl_up(s, off, 64);
            if (t >= off) s += y;
        }
        wsum[t] = s;
    }
    __syncthreads();
    int wo = w ? wsum[w - 1] : 0;
    if (i < n) rowp[i] = wo + x - v;            // chunk-local exclusive
    if (t == 0) bsum[b] = wsum[15];             // chunk total
}

// phase 2: exclusive scan of <=64 chunk totals (single wave)
__global__ __launch_bounds__(64) void k_scan2(int* __restrict__ bsum, int nb) {
    int lane = threadIdx.x;
    int v = (lane < nb) ? bsum[lane] : 0;
    int x = v;
#pragma unroll
    for (int off = 1; off < 64; off <<= 1) {
        int y = __shfl_up(x, off, 64);
        if (lane >= off) x += y;
    }
    int total = __shfl(x, nb - 1, 64);
    if (lane < nb) bsum[lane] = x - v;          // exclusive
    if (lane == 0) bsum[nb] = total;
}

// phase 3: add chunk offsets; write rowp[n] = total
__global__ __launch_bounds__(1024) void k_scan3(const int* __restrict__ bsum,
                                                int* __restrict__ rowp, int n, int nb) {
    int i = blockIdx.x * 1024 + threadIdx.x;
    if (i < n) rowp[i] += bsum[i >> 10];
    else if (i == n) rowp[n] = bsum[nb];
}

__global__ void k_csr_fill(const int* __restrict__ ei, const int* __restrict__ rowp,
                           int* __restrict__ fill, int* __restrict__ col, int E, int n) {
    int idx = blockIdx.x * blockDim.x + threadIdx.x;
    if (idx < E) {
        int d = ei[E + idx];
        int s = ei[idx];
        int pos = atomicAdd(&fill[d], 1);
        col[rowp[d] + pos] = s;
    } else if (idx < E + n) {
        int nd = idx - E;
        int pos = atomicAdd(&fill[nd], 1);
        col[rowp[nd] + pos] = nd;   // self loop
    }
}

// ---- row inverse L2 norm, bf16 rows (H=512) --------------------------------
__global__ __launch_bounds__(256) void k_norm_bf16(const unsigned short* __restrict__ h,
                                                   float* __restrict__ invn, int n) {
    int row = blockIdx.x * 4 + (threadIdx.x >> 6);
    int lane = threadIdx.x & 63;
    if (row >= n) return;
    ushort8 v = *(const ushort8*)(h + (long)row * 512 + lane * 8);
    float s = 0.f;
#pragma unroll
    for (int e = 0; e < 8; ++e) { float f = bf2f(v[e]); s += f * f; }
#pragma unroll
    for (int off = 32; off; off >>= 1) s += __shfl_xor(s, off, 64);
    if (lane == 0) invn[row] = 1.f / fmaxf(sqrtf(s), 1e-12f);
}

// ---- AGNN propagation: bf16 rows, one wave per dst, single-pass -----------
// Optionally fuses the inv-L2-norm of the OUTPUT row (for the next prop).
__global__ __launch_bounds__(256) void k_agnn(
    const unsigned short* __restrict__ h, const float* __restrict__ invn,
    const int* __restrict__ rowp, const int* __restrict__ col,
    const float* __restrict__ beta_ptr, unsigned short* __restrict__ out,
    float* __restrict__ invn_out, int nNodes) {
    int dst = blockIdx.x * 4 + (threadIdx.x >> 6);
    int lane = threadIdx.x & 63;
    if (dst >= nNodes) return;
    float beta = beta_ptr ? beta_ptr[0] : 1.0f;
    ushort8 hdv = *(const ushort8*)(h + (long)dst * 512 + lane * 8);
    float hd[8];
#pragma unroll
    for (int e = 0; e < 8; ++e) hd[e] = bf2f(hdv[e]);
    float coef = beta * invn[dst];
    int s0 = rowp[dst], s1 = rowp[dst + 1];

    float m = -1e30f, ssum = 0.f;
    float acc[8] = {0.f, 0.f, 0.f, 0.f, 0.f, 0.f, 0.f, 0.f};

    for (int base = s0; base < s1; base += 64) {
        int cnt = min(s1 - base, 64);
        int gi = base + lane; if (gi >= s1) gi = s1 - 1;
        int idxl = col[gi];              // batch of up to 64 edge indices
        float vinl = invn[idxl];         // batch of src inv-norms
        int src0 = __shfl(idxl, 0, 64);
        ushort8 nxt = *(const ushort8*)(h + (long)src0 * 512 + lane * 8);
        for (int j = 0; j < cnt; ++j) {
            ushort8 cur = nxt;
            if (j + 1 < cnt) {
                int sn = __shfl(idxl, j + 1, 64);
                nxt = *(const ushort8*)(h + (long)sn * 512 + lane * 8);  // prefetch
            }
            float a[8];
#pragma unroll
            for (int e = 0; e < 8; ++e) a[e] = bf2f(cur[e]);
            float p = a[0] * hd[0] + a[1] * hd[1] + a[2] * hd[2] + a[3] * hd[3] +
                      a[4] * hd[4] + a[5] * hd[5] + a[6] * hd[6] + a[7] * hd[7];
#pragma unroll
            for (int off = 32; off; off >>= 1) p += __shfl_xor(p, off, 64);
            float alpha = coef * __shfl(vinl, j, 64) * p;
            if (alpha > m) {             // wave-uniform (alpha fully reduced)
                float sc = __expf(m - alpha);
                ssum *= sc;
#pragma unroll
                for (int e = 0; e < 8; ++e) acc[e] *= sc;
                m = alpha;
            }
            float wgt = __expf(alpha - m);
            ssum += wgt;
#pragma unroll
            for (int e = 0; e < 8; ++e) acc[e] += wgt * a[e];
        }
    }
    float inv_s = 1.f / ssum;
#pragma unroll
    for (int e = 0; e < 8; ++e) acc[e] *= inv_s;

    uint4v o = { cvtpk(acc[0], acc[1]), cvtpk(acc[2], acc[3]),
                 cvtpk(acc[4], acc[5]), cvtpk(acc[6], acc[7]) };
    *(uint4v*)(out + (long)dst * 512 + lane * 8) = o;

    if (invn_out) {                      // fused output norm (feeds next prop)
        float s = 0.f;
#pragma unroll
        for (int e = 0; e < 8; ++e) s += acc[e] * acc[e];
#pragma unroll
        for (int off = 32; off; off >>= 1) s += __shfl_xor(s, off, 64);
        if (lane == 0) invn_out[dst] = 1.f / fmaxf(sqrtf(s), 1e-12f);
    }
}

// ---- graph boundaries in sorted batch -------------------------------------
__global__ void k_bounds(const int* __restrict__ batch, int* __restrict__ starts,
                         int n, int G) {
    int g = blockIdx.x * blockDim.x + threadIdx.x;
    if (g > G) return;
    int lo = 0, hi = n;
    while (lo < hi) {
        int mid = (lo + hi) >> 1;
        if (batch[mid] < g) lo = mid + 1; else hi = mid;
    }
    starts[g] = lo;
}

// ---- per-graph max/mean pool (H2=256) -------------------------------------
__global__ __launch_bounds__(256) void k_pool(const float* __restrict__ h3,
                                              const int* __restrict__ starts,
                                              float* __restrict__ pooled) {
    int g = blockIdx.x;
    int t = threadIdx.x;
    int s = starts[g], e = starts[g + 1];
    float mx = -3.402823466e38f, sm = 0.f;
    int r = s;
    for (; r + 4 <= e; r += 4) {          // ILP unroll
        float v0 = h3[(long)(r + 0) * 256 + t];
        float v1 = h3[(long)(r + 1) * 256 + t];
        float v2 = h3[(long)(r + 2) * 256 + t];
        float v3 = h3[(long)(r + 3) * 256 + t];
        mx = fmaxf(mx, fmaxf(fmaxf(v0, v1), fmaxf(v2, v3)));
        sm += (v0 + v1) + (v2 + v3);
    }
    for (; r < e; ++r) {
        float v = h3[(long)r * 256 + t];
        mx = fmaxf(mx, v); sm += v;
    }
    float cnt = fmaxf((float)(e - s), 1.f);
    pooled[g * 512 + t] = mx;
    pooled[g * 512 + 256 + t] = sm / cnt;
}

// ---- final tiny GEMM: out[G][C] = pooled[G][512] @ W3[512][C] + b3 --------
__global__ __launch_bounds__(64) void k_final(const float* __restrict__ pooled,
                                              const float* __restrict__ W3,
                                              const float* __restrict__ b3,
                                              float* __restrict__ out, int C) {
    int g = blockIdx.x;
    int lane = threadIdx.x;
    for (int c = 0; c < C; c++) {
        float p = 0.f;
        for (int k = lane; k < 512; k += 64) p += pooled[g * 512 + k] * W3[k * C + c];
#pragma unroll
        for (int off = 32; off; off >>= 1) p += __shfl_xor(p, off, 64);
        if (lane == 0) out[g * C + c] = p + b3[c];
    }
}

// ---------------------------------------------------------------------------
extern "C" void kernel_launch(void* const* d_in, const int* in_sizes, int n_in,
                              void* d_out, int out_size, void* d_ws, size_t ws_size,
                              hipStream_t stream) {
    const float* x     = (const float*)d_in[0];
    const int*   ei    = (const int*)d_in[1];
    const int*   batch = (const int*)d_in[2];
    const float* W1    = (const float*)d_in[3];
    const float* b1    = (const float*)d_in[4];
    const float* beta2 = (const float*)d_in[5];
    const float* W2    = (const float*)d_in[6];
    const float* b2    = (const float*)d_in[7];
    const float* W3    = (const float*)d_in[8];
    const float* b3    = (const float*)d_in[9];
    float* out = (float*)d_out;

    const int N = in_sizes[2];          // 30000
    const int E = in_sizes[1] / 2;      // 480000
    const int F_IN = in_sizes[0] / N;   // 1280
    const int H = in_sizes[4];          // 512
    const int H2 = in_sizes[7];         // 256
    const int C = in_sizes[9];          // 10
    const int G = out_size / C;         // 64

    char* ws = (char*)d_ws;
    unsigned short* H1B = (unsigned short*)(ws + 0);            // 30.72 MB bf16
    unsigned short* HPB = (unsigned short*)(ws + 31000000L);    // 30.72 MB bf16
    unsigned short* H2B = (unsigned short*)(ws + 62000000L);    // 30.72 MB bf16
    float*          H3  = (float*)(ws + 0);                     // 61.44 MB f32 (over H1B/HPB, both dead)
    unsigned short* W1T = (unsigned short*)(ws + 93000000L);    // 1.31 MB
    unsigned short* W2T = (unsigned short*)(ws + 94500000L);    // 0.26 MB
    float* INVN_A = (float*)(ws + 95000000L);                   // 120 KB
    float* INVN_B = (float*)(ws + 95200000L);                   // 120 KB
    int*   CNT    = (int*)(ws + 95400000L);
    int*   FILL   = (int*)(ws + 95600000L);
    int*   ROWP   = (int*)(ws + 95800000L);
    int*   COL    = (int*)(ws + 96000000L);                     // 2.04 MB
    int*   BSUM   = (int*)(ws + 98100000L);
    int*   START  = (int*)(ws + 98110000L);
    float* POOLED = (float*)(ws + 98120000L);                   // 131 KB

    // 1. weight transposes (f32 -> bf16 [N][K])
    { dim3 g1(F_IN / 32, H / 32); k_transpose_bf16<<<g1, 256, 0, stream>>>(W1, W1T, F_IN, H); }
    { dim3 g2(H / 32, H2 / 32);   k_transpose_bf16<<<g2, 256, 0, stream>>>(W2, W2T, H, H2); }

    // 2. CSR (incoming edges + self loops)
    int nb = (N + 1023) / 1024;   // 30
    k_csr_init<<<(N + 255) / 256, 256, 0, stream>>>(CNT, FILL, N);
    k_csr_count<<<(E + 255) / 256, 256, 0, stream>>>(ei, CNT, E);
    k_scan1<<<nb, 1024, 0, stream>>>(CNT, ROWP, BSUM, N);
    k_scan2<<<1, 64, 0, stream>>>(BSUM, nb);
    k_scan3<<<(N + 1 + 1023) / 1024, 1024, 0, stream>>>(BSUM, ROWP, N, nb);
    k_csr_fill<<<(E + N + 255) / 256, 256, 0, stream>>>(ei, ROWP, FILL, COL, E, N);

    // 3. GEMM1: H1B = bf16(relu(x @ W1 + b1))   [N,512] (f32 A reg-staged)
    {
        dim3 grid(H / 128, (N + 127) / 128);
        k_gemm_bias_relu<1280, 512, true, true><<<grid, 256, 0, stream>>>(x, W1T, b1, H1B, N);
    }

    // 4. prop1 (beta=1): HPB = AGNN(H1B), fused invn of HPB -> INVN_B
    k_norm_bf16<<<(N + 3) / 4, 256, 0, stream>>>(H1B, INVN_A, N);
    k_agnn<<<(N + 3) / 4, 256, 0, stream>>>(H1B, INVN_A, ROWP, COL, nullptr, HPB, INVN_B, N);

    // 5. prop2 (beta=beta2): H2B = AGNN(HPB)
    k_agnn<<<(N + 3) / 4, 256, 0, stream>>>(HPB, INVN_B, ROWP, COL, beta2, H2B, nullptr, N);

    // 6. GEMM2: H3 = relu(H2B @ W2 + b2)   [N,256] f32
    {
        dim3 grid(H2 / 128, (N + 127) / 128);
        k_gemm_bias_relu<512, 256, false, false><<<grid, 256, 0, stream>>>(H2B, W2T, b2, H3, N);
    }

    // 7. pool + final linear
    k_bounds<<<1, 128, 0, stream>>>(batch, START, N, G);
    k_pool<<<G, 256, 0, stream>>>(H3, START, POOLED);
    k_final<<<G, 64, 0, stream>>>(POOLED, W3, b3, out, C);
}

// Round 4
// 400.154 us; speedup vs baseline: 3.2934x; 1.0999x over previous
//
#include <hip/hip_runtime.h>
#include <hip/hip_bf16.h>
#include <cstdint>

// ---------------------------------------------------------------------------
// Model: h=relu(x@W1+b1); h=AGNN(h,beta=1); h=AGNN(h,beta2); h=relu(h@W2+b2);
//        out = concat(segmax(h,batch), segmean(h,batch)) @ W3 + b3
// N=30000, E=480000, F_IN=1280, H=512, H2=256, G=64, C=10
// bf16 feature rows through propagation; read-once wide-BN MFMA GEMMs.
// ---------------------------------------------------------------------------

typedef __attribute__((ext_vector_type(8))) short bf16x8;
typedef __attribute__((ext_vector_type(4))) float f32x4;
typedef __attribute__((ext_vector_type(8))) unsigned short ushort8;
typedef __attribute__((ext_vector_type(4))) unsigned short ushort4v;
typedef __attribute__((ext_vector_type(4))) unsigned int uint4v;

__device__ inline unsigned short f2bf(float f) {
    unsigned int u = __float_as_uint(f);
    u += 0x7FFFu + ((u >> 16) & 1u);   // RNE
    return (unsigned short)(u >> 16);
}

__device__ __forceinline__ float bf2f(unsigned short u) {
    return __uint_as_float(((unsigned int)u) << 16);
}

// packed f32x2 -> bf16x2 (RNE), single HW instruction on gfx950
__device__ __forceinline__ unsigned int cvtpk(float lo, float hi) {
    unsigned int r;
    asm("v_cvt_pk_bf16_f32 %0, %1, %2" : "=v"(r) : "v"(lo), "v"(hi));
    return r;
}

__device__ __forceinline__ void gload_lds16(const void* g, void* l) {
    __builtin_amdgcn_global_load_lds(
        (const __attribute__((address_space(1))) void*)g,
        (__attribute__((address_space(3))) void*)l, 16, 0, 0);
}

// ---- tiled transpose: W [K][N] f32 -> Wt [N][K] bf16 (K,N multiples of 32) -
__global__ __launch_bounds__(256) void k_transpose_bf16(
    const float* __restrict__ W, unsigned short* __restrict__ Wt, int K, int N) {
    __shared__ unsigned short t[32][33];
    int k0 = blockIdx.x * 32, n0 = blockIdx.y * 32;
    int tr = threadIdx.x >> 3;          // 0..31
    int tc = (threadIdx.x & 7) * 4;     // 0,4,...,28
    float4 v = *(const float4*)(W + (long)(k0 + tr) * N + n0 + tc);
    t[tr][tc + 0] = f2bf(v.x); t[tr][tc + 1] = f2bf(v.y);
    t[tr][tc + 2] = f2bf(v.z); t[tr][tc + 3] = f2bf(v.w);
    __syncthreads();
    ushort4v o = { t[tc + 0][tr], t[tc + 1][tr], t[tc + 2][tr], t[tc + 3][tr] };
    *(ushort4v*)(Wt + (long)(n0 + tr) * K + k0 + tc) = o;
}

// ---- wide-BN MFMA GEMM: C[M][N] = relu(A[M][K] @ Bt[N][K]^T + bias) -------
// BN = N (grid is 1D over 128-row m-tiles) -> A is read from global ONCE.
// WN waves in N (each 128 cols), 2 waves in M (each 64 rows); BK=32.
// Double-buffered LDS; one barrier per K-step; next-tile loads issued before
// the current tile's MFMAs (T3 minimum-2-phase).
// AF32: A is f32 in global, reg-staged + packed to bf16 (contiguous ds_write).
template <int K, int N, int WN, bool AF32, bool OUTBF16>
__global__ __launch_bounds__(WN * 128, 2) void k_gemm_bias_relu(
    const void* __restrict__ Av, const unsigned short* __restrict__ Bt,
    const float* __restrict__ bias, void* __restrict__ Cv, int M) {
    constexpr int NW = 2 * WN;          // waves per block
    __shared__ unsigned short As[2][128 * 32];
    __shared__ unsigned short Bs[2][N * 32];
    int tid = threadIdx.x;
    int w = tid >> 6, l = tid & 63;
    int wm = w / WN, wn = w % WN;
    int mBase = blockIdx.x * 128;

    const float* Af = (const float*)Av;
    const unsigned short* Ab = (const unsigned short*)Av;

    // AF32 reg-staging geometry: thread t owns 8 consecutive f32 (16B bf16)
    int arow = tid >> 2;                  // 0..127
    int acol = (tid & 3) * 8;             // 0,8,16,24
    long aRowG = mBase + arow; if (aRowG >= M) aRowG = M - 1;
    const float* aptr = AF32 ? (Af + aRowG * K + acol) : nullptr;

    // ---- staging helpers --------------------------------------------------
    auto stageB = [&](int b, int k0) {
#pragma unroll
        for (int o = 0; o < 4; ++o) {
            int row = w * 64 + o * 16;                       // wave-uniform
            gload_lds16(Bt + (long)(row + (l >> 2)) * K + k0 + (l & 3) * 8,
                        &Bs[b][row * 32]);
        }
    };
    auto stageAbf = [&](int b, int k0) {
#pragma unroll
        for (int o = 0; o < 8 / NW; ++o) {
            int row = (w * (8 / NW) + o) * 16;               // wave-uniform
            long gr = mBase + row + (l >> 2); if (gr >= M) gr = M - 1;
            gload_lds16(Ab + gr * K + k0 + (l & 3) * 8, &As[b][row * 32]);
        }
    };

    f32x4 acc[4][8] = {};
    constexpr int NSTEP = K / 32;

    // ---- prologue: stage k0 = 0 into buffer 0 ----------------------------
    stageB(0, 0);
    if constexpr (AF32) {
        float4 f0 = *(const float4*)(aptr);
        float4 f1 = *(const float4*)(aptr + 4);
        uint4v p = { cvtpk(f0.x, f0.y), cvtpk(f0.z, f0.w),
                     cvtpk(f1.x, f1.y), cvtpk(f1.z, f1.w) };
        *(uint4v*)(&As[0][arow * 32 + acol]) = p;
    } else {
        stageAbf(0, 0);
    }
    __syncthreads();

    int s = 0;
    for (int step = 0; step < NSTEP; ++step, s ^= 1) {
        int nk = (step + 1) * 32;
        float4 f0, f1;
        if (nk < K) {                       // issue next-tile loads FIRST
            stageB(s ^ 1, nk);
            if constexpr (AF32) {
                f0 = *(const float4*)(aptr + nk);
                f1 = *(const float4*)(aptr + nk + 4);
            } else {
                stageAbf(s ^ 1, nk);
            }
        }
        // ---- compute current buffer --------------------------------------
        bf16x8 af[4], bfr[8];
#pragma unroll
        for (int m = 0; m < 4; ++m)
            af[m] = *(const bf16x8*)(&As[s][(wm * 64 + m * 16 + (l & 15)) * 32 + (l >> 4) * 8]);
#pragma unroll
        for (int n = 0; n < 8; ++n)
            bfr[n] = *(const bf16x8*)(&Bs[s][(wn * 128 + n * 16 + (l & 15)) * 32 + (l >> 4) * 8]);
#pragma unroll
        for (int m = 0; m < 4; ++m)
#pragma unroll
            for (int n = 0; n < 8; ++n)
                acc[m][n] = __builtin_amdgcn_mfma_f32_16x16x32_bf16(
                    af[m], bfr[n], acc[m][n], 0, 0, 0);
        if constexpr (AF32) {
            if (nk < K) {                    // write next A after MFMAs
                uint4v p = { cvtpk(f0.x, f0.y), cvtpk(f0.z, f0.w),
                             cvtpk(f1.x, f1.y), cvtpk(f1.z, f1.w) };
                *(uint4v*)(&As[s ^ 1][arow * 32 + acol]) = p;
            }
        }
        __syncthreads();                     // next buffer ready; cur reads done
    }

    // ---- epilogue: row=(l>>4)*4+r, col=l&15 (HW-verified) -----------------
#pragma unroll
    for (int m = 0; m < 4; ++m) {
        int row = mBase + wm * 64 + m * 16 + (l >> 4) * 4;
#pragma unroll
        for (int n = 0; n < 8; ++n) {
            int colg = wn * 128 + n * 16 + (l & 15);
            float bv = bias[colg];
#pragma unroll
            for (int r = 0; r < 4; ++r) {
                if (row + r < M) {
                    float v = fmaxf(acc[m][n][r] + bv, 0.f);
                    if constexpr (OUTBF16)
                        ((unsigned short*)Cv)[(long)(row + r) * N + colg] = f2bf(v);
                    else
                        ((float*)Cv)[(long)(row + r) * N + colg] = v;
                }
            }
        }
    }
}

// ---- CSR build ------------------------------------------------------------
__global__ void k_csr_init(int* __restrict__ cnt, int* __restrict__ fill, int n) {
    int i = blockIdx.x * blockDim.x + threadIdx.x;
    if (i < n) { cnt[i] = 1; fill[i] = 0; }   // 1 = self loop
}

__global__ void k_csr_count(const int* __restrict__ ei, int* __restrict__ cnt, int E) {
    int e = blockIdx.x * blockDim.x + threadIdx.x;
    if (e < E) atomicAdd(&cnt[ei[E + e]], 1);   // dst row
}

// hierarchical exclusive scan: phase 1 (per-1024-chunk scan + chunk total)
__global__ __launch_bounds__(1024) void k_scan1(const int* __restrict__ cnt,
                                                int* __restrict__ rowp,
                                                int* __restrict__ bsum, int n) {
    __shared__ int wsum[16];
    int b = blockIdx.x, t = threadIdx.x, lane = t & 63, w = t >> 6;
    int i = b * 1024 + t;
    int v = (i < n) ? cnt[i] : 0;
    int x = v;
#pragma unroll
    for (int off = 1; off < 64; off <<= 1) {
        int y = __shfl_up(x, off, 64);
        if (lane >= off) x += y;
    }
    if (lane == 63) wsum[w] = x;
    __syncthreads();
    if (t < 16) {
        int s = wsum[t];
#pragma unroll
        for (int off = 1; off < 16; off <<= 1) {
            int y = __shfl_up(s, off, 64);
            if (t >= off) s += y;
        }
        wsum[t] = s;
    }
    __syncthreads();
    int wo = w ? wsum[w - 1] : 0;
    if (i < n) rowp[i] = wo + x - v;            // chunk-local exclusive
    if (t == 0) bsum[b] = wsum[15];             // chunk total
}

// phase 2: exclusive scan of <=64 chunk totals (single wave)
__global__ __launch_bounds__(64) void k_scan2(int* __restrict__ bsum, int nb) {
    int lane = threadIdx.x;
    int v = (lane < nb) ? bsum[lane] : 0;
    int x = v;
#pragma unroll
    for (int off = 1; off < 64; off <<= 1) {
        int y = __shfl_up(x, off, 64);
        if (lane >= off) x += y;
    }
    int total = __shfl(x, nb - 1, 64);
    if (lane < nb) bsum[lane] = x - v;          // exclusive
    if (lane == 0) bsum[nb] = total;
}

// phase 3: add chunk offsets; write rowp[n] = total
__global__ __launch_bounds__(1024) void k_scan3(const int* __restrict__ bsum,
                                                int* __restrict__ rowp, int n, int nb) {
    int i = blockIdx.x * 1024 + threadIdx.x;
    if (i < n) rowp[i] += bsum[i >> 10];
    else if (i == n) rowp[n] = bsum[nb];
}

__global__ void k_csr_fill(const int* __restrict__ ei, const int* __restrict__ rowp,
                           int* __restrict__ fill, int* __restrict__ col, int E, int n) {
    int idx = blockIdx.x * blockDim.x + threadIdx.x;
    if (idx < E) {
        int d = ei[E + idx];
        int s = ei[idx];
        int pos = atomicAdd(&fill[d], 1);
        col[rowp[d] + pos] = s;
    } else if (idx < E + n) {
        int nd = idx - E;
        int pos = atomicAdd(&fill[nd], 1);
        col[rowp[nd] + pos] = nd;   // self loop
    }
}

// ---- row inverse L2 norm, bf16 rows (H=512) --------------------------------
__global__ __launch_bounds__(256) void k_norm_bf16(const unsigned short* __restrict__ h,
                                                   float* __restrict__ invn, int n) {
    int row = blockIdx.x * 4 + (threadIdx.x >> 6);
    int lane = threadIdx.x & 63;
    if (row >= n) return;
    ushort8 v = *(const ushort8*)(h + (long)row * 512 + lane * 8);
    float s = 0.f;
#pragma unroll
    for (int e = 0; e < 8; ++e) { float f = bf2f(v[e]); s += f * f; }
#pragma unroll
    for (int off = 32; off; off >>= 1) s += __shfl_xor(s, off, 64);
    if (lane == 0) invn[row] = 1.f / fmaxf(sqrtf(s), 1e-12f);
}

// ---- AGNN propagation: bf16 rows, one wave per dst, single-pass -----------
// Optionally fuses the inv-L2-norm of the OUTPUT row (for the next prop).
__global__ __launch_bounds__(256) void k_agnn(
    const unsigned short* __restrict__ h, const float* __restrict__ invn,
    const int* __restrict__ rowp, const int* __restrict__ col,
    const float* __restrict__ beta_ptr, unsigned short* __restrict__ out,
    float* __restrict__ invn_out, int nNodes) {
    int dst = blockIdx.x * 4 + (threadIdx.x >> 6);
    int lane = threadIdx.x & 63;
    if (dst >= nNodes) return;
    float beta = beta_ptr ? beta_ptr[0] : 1.0f;
    ushort8 hdv = *(const ushort8*)(h + (long)dst * 512 + lane * 8);
    float hd[8];
#pragma unroll
    for (int e = 0; e < 8; ++e) hd[e] = bf2f(hdv[e]);
    float coef = beta * invn[dst];
    int s0 = rowp[dst], s1 = rowp[dst + 1];

    float m = -1e30f, ssum = 0.f;
    float acc[8] = {0.f, 0.f, 0.f, 0.f, 0.f, 0.f, 0.f, 0.f};

    for (int base = s0; base < s1; base += 64) {
        int cnt = min(s1 - base, 64);
        int gi = base + lane; if (gi >= s1) gi = s1 - 1;
        int idxl = col[gi];              // batch of up to 64 edge indices
        float vinl = invn[idxl];         // batch of src inv-norms
        int src0 = __shfl(idxl, 0, 64);
        ushort8 nxt = *(const ushort8*)(h + (long)src0 * 512 + lane * 8);
        for (int j = 0; j < cnt; ++j) {
            ushort8 cur = nxt;
            if (j + 1 < cnt) {
                int sn = __shfl(idxl, j + 1, 64);
                nxt = *(const ushort8*)(h + (long)sn * 512 + lane * 8);  // prefetch
            }
            float a[8];
#pragma unroll
            for (int e = 0; e < 8; ++e) a[e] = bf2f(cur[e]);
            float p = a[0] * hd[0] + a[1] * hd[1] + a[2] * hd[2] + a[3] * hd[3] +
                      a[4] * hd[4] + a[5] * hd[5] + a[6] * hd[6] + a[7] * hd[7];
#pragma unroll
            for (int off = 32; off; off >>= 1) p += __shfl_xor(p, off, 64);
            float alpha = coef * __shfl(vinl, j, 64) * p;
            if (alpha > m) {             // wave-uniform (alpha fully reduced)
                float sc = __expf(m - alpha);
                ssum *= sc;
#pragma unroll
                for (int e = 0; e < 8; ++e) acc[e] *= sc;
                m = alpha;
            }
            float wgt = __expf(alpha - m);
            ssum += wgt;
#pragma unroll
            for (int e = 0; e < 8; ++e) acc[e] += wgt * a[e];
        }
    }
    float inv_s = 1.f / ssum;
#pragma unroll
    for (int e = 0; e < 8; ++e) acc[e] *= inv_s;

    uint4v o = { cvtpk(acc[0], acc[1]), cvtpk(acc[2], acc[3]),
                 cvtpk(acc[4], acc[5]), cvtpk(acc[6], acc[7]) };
    *(uint4v*)(out + (long)dst * 512 + lane * 8) = o;

    if (invn_out) {                      // fused output norm (feeds next prop)
        float s = 0.f;
#pragma unroll
        for (int e = 0; e < 8; ++e) s += acc[e] * acc[e];
#pragma unroll
        for (int off = 32; off; off >>= 1) s += __shfl_xor(s, off, 64);
        if (lane == 0) invn_out[dst] = 1.f / fmaxf(sqrtf(s), 1e-12f);
    }
}

// ---- graph boundaries in sorted batch -------------------------------------
__global__ void k_bounds(const int* __restrict__ batch, int* __restrict__ starts,
                         int n, int G) {
    int g = blockIdx.x * blockDim.x + threadIdx.x;
    if (g > G) return;
    int lo = 0, hi = n;
    while (lo < hi) {
        int mid = (lo + hi) >> 1;
        if (batch[mid] < g) lo = mid + 1; else hi = mid;
    }
    starts[g] = lo;
}

// ---- per-graph max/mean pool (H2=256) -------------------------------------
__global__ __launch_bounds__(256) void k_pool(const float* __restrict__ h3,
                                              const int* __restrict__ starts,
                                              float* __restrict__ pooled) {
    int g = blockIdx.x;
    int t = threadIdx.x;
    int s = starts[g], e = starts[g + 1];
    float mx = -3.402823466e38f, sm = 0.f;
    int r = s;
    for (; r + 4 <= e; r += 4) {          // ILP unroll
        float v0 = h3[(long)(r + 0) * 256 + t];
        float v1 = h3[(long)(r + 1) * 256 + t];
        float v2 = h3[(long)(r + 2) * 256 + t];
        float v3 = h3[(long)(r + 3) * 256 + t];
        mx = fmaxf(mx, fmaxf(fmaxf(v0, v1), fmaxf(v2, v3)));
        sm += (v0 + v1) + (v2 + v3);
    }
    for (; r < e; ++r) {
        float v = h3[(long)r * 256 + t];
        mx = fmaxf(mx, v); sm += v;
    }
    float cnt = fmaxf((float)(e - s), 1.f);
    pooled[g * 512 + t] = mx;
    pooled[g * 512 + 256 + t] = sm / cnt;
}

// ---- final tiny GEMM: out[G][C] = pooled[G][512] @ W3[512][C] + b3 --------
__global__ __launch_bounds__(64) void k_final(const float* __restrict__ pooled,
                                              const float* __restrict__ W3,
                                              const float* __restrict__ b3,
                                              float* __restrict__ out, int C) {
    int g = blockIdx.x;
    int lane = threadIdx.x;
    for (int c = 0; c < C; c++) {
        float p = 0.f;
        for (int k = lane; k < 512; k += 64) p += pooled[g * 512 + k] * W3[k * C + c];
#pragma unroll
        for (int off = 32; off; off >>= 1) p += __shfl_xor(p, off, 64);
        if (lane == 0) out[g * C + c] = p + b3[c];
    }
}

// ---------------------------------------------------------------------------
extern "C" void kernel_launch(void* const* d_in, const int* in_sizes, int n_in,
                              void* d_out, int out_size, void* d_ws, size_t ws_size,
                              hipStream_t stream) {
    const float* x     = (const float*)d_in[0];
    const int*   ei    = (const int*)d_in[1];
    const int*   batch = (const int*)d_in[2];
    const float* W1    = (const float*)d_in[3];
    const float* b1    = (const float*)d_in[4];
    const float* beta2 = (const float*)d_in[5];
    const float* W2    = (const float*)d_in[6];
    const float* b2    = (const float*)d_in[7];
    const float* W3    = (const float*)d_in[8];
    const float* b3    = (const float*)d_in[9];
    float* out = (float*)d_out;

    const int N = in_sizes[2];          // 30000
    const int E = in_sizes[1] / 2;      // 480000
    const int F_IN = in_sizes[0] / N;   // 1280
    const int H = in_sizes[4];          // 512
    const int H2 = in_sizes[7];         // 256
    const int C = in_sizes[9];          // 10
    const int G = out_size / C;         // 64

    char* ws = (char*)d_ws;
    unsigned short* H1B = (unsigned short*)(ws + 0);            // 30.72 MB bf16
    unsigned short* HPB = (unsigned short*)(ws + 31000000L);    // 30.72 MB bf16
    unsigned short* H2B = (unsigned short*)(ws + 62000000L);    // 30.72 MB bf16
    float*          H3  = (float*)(ws + 0);                     // 61.44 MB f32 (over H1B/HPB, both dead)
    unsigned short* W1T = (unsigned short*)(ws + 93000000L);    // 1.31 MB
    unsigned short* W2T = (unsigned short*)(ws + 94500000L);    // 0.26 MB
    float* INVN_A = (float*)(ws + 95000000L);                   // 120 KB
    float* INVN_B = (float*)(ws + 95200000L);                   // 120 KB
    int*   CNT    = (int*)(ws + 95400000L);
    int*   FILL   = (int*)(ws + 95600000L);
    int*   ROWP   = (int*)(ws + 95800000L);
    int*   COL    = (int*)(ws + 96000000L);                     // 2.04 MB
    int*   BSUM   = (int*)(ws + 98100000L);
    int*   START  = (int*)(ws + 98110000L);
    float* POOLED = (float*)(ws + 98120000L);                   // 131 KB

    // 1. weight transposes (f32 -> bf16 [N][K])
    { dim3 g1(F_IN / 32, H / 32); k_transpose_bf16<<<g1, 256, 0, stream>>>(W1, W1T, F_IN, H); }
    { dim3 g2(H / 32, H2 / 32);   k_transpose_bf16<<<g2, 256, 0, stream>>>(W2, W2T, H, H2); }

    // 2. CSR (incoming edges + self loops)
    int nb = (N + 1023) / 1024;   // 30
    k_csr_init<<<(N + 255) / 256, 256, 0, stream>>>(CNT, FILL, N);
    k_csr_count<<<(E + 255) / 256, 256, 0, stream>>>(ei, CNT, E);
    k_scan1<<<nb, 1024, 0, stream>>>(CNT, ROWP, BSUM, N);
    k_scan2<<<1, 64, 0, stream>>>(BSUM, nb);
    k_scan3<<<(N + 1 + 1023) / 1024, 1024, 0, stream>>>(BSUM, ROWP, N, nb);
    k_csr_fill<<<(E + N + 255) / 256, 256, 0, stream>>>(ei, ROWP, FILL, COL, E, N);

    // 3. GEMM1: H1B = bf16(relu(x @ W1 + b1))  [N,512]; BN=512 read-once A
    k_gemm_bias_relu<1280, 512, 4, true, true>
        <<<(N + 127) / 128, 512, 0, stream>>>(x, W1T, b1, H1B, N);

    // 4. prop1 (beta=1): HPB = AGNN(H1B), fused invn of HPB -> INVN_B
    k_norm_bf16<<<(N + 3) / 4, 256, 0, stream>>>(H1B, INVN_A, N);
    k_agnn<<<(N + 3) / 4, 256, 0, stream>>>(H1B, INVN_A, ROWP, COL, nullptr, HPB, INVN_B, N);

    // 5. prop2 (beta=beta2): H2B = AGNN(HPB)
    k_agnn<<<(N + 3) / 4, 256, 0, stream>>>(HPB, INVN_B, ROWP, COL, beta2, H2B, nullptr, N);

    // 6. GEMM2: H3 = relu(H2B @ W2 + b2)  [N,256] f32; BN=256 read-once A
    k_gemm_bias_relu<512, 256, 2, false, false>
        <<<(N + 127) / 128, 256, 0, stream>>>(H2B, W2T, b2, H3, N);

    // 7. pool + final linear
    k_bounds<<<1, 128, 0, stream>>>(batch, START, N, G);
    k_pool<<<G, 256, 0, stream>>>(H3, START, POOLED);
    k_final<<<G, 64, 0, stream>>>(POOLED, W3, b3, out, C);
}

// Round 5
// 395.114 us; speedup vs baseline: 3.3354x; 1.0128x over previous
//
#include <hip/hip_runtime.h>
#include <hip/hip_bf16.h>
#include <cstdint>

// ---------------------------------------------------------------------------
// Model: h=relu(x@W1+b1); h=AGNN(h,beta=1); h=AGNN(h,beta2); h=relu(h@W2+b2);
//        out = concat(segmax(h,batch), segmean(h,batch)) @ W3 + b3
// N=30000, E=480000, F_IN=1280, H=512, H2=256, G=64, C=10
// bf16 feature rows through propagation; read-once wide-BN MFMA GEMMs with
// XOR-swizzled LDS (conflict-free ds_read_b128), 64-row tiles for 2+ blocks/CU.
// ---------------------------------------------------------------------------

typedef __attribute__((ext_vector_type(8))) short bf16x8;
typedef __attribute__((ext_vector_type(4))) float f32x4;
typedef __attribute__((ext_vector_type(8))) unsigned short ushort8;
typedef __attribute__((ext_vector_type(4))) unsigned short ushort4v;
typedef __attribute__((ext_vector_type(4))) unsigned int uint4v;

__device__ inline unsigned short f2bf(float f) {
    unsigned int u = __float_as_uint(f);
    u += 0x7FFFu + ((u >> 16) & 1u);   // RNE
    return (unsigned short)(u >> 16);
}

__device__ __forceinline__ float bf2f(unsigned short u) {
    return __uint_as_float(((unsigned int)u) << 16);
}

// packed f32x2 -> bf16x2 (RNE), single HW instruction on gfx950
__device__ __forceinline__ unsigned int cvtpk(float lo, float hi) {
    unsigned int r;
    asm("v_cvt_pk_bf16_f32 %0, %1, %2" : "=v"(r) : "v"(lo), "v"(hi));
    return r;
}

__device__ __forceinline__ void gload_lds16(const void* g, void* l) {
    __builtin_amdgcn_global_load_lds(
        (const __attribute__((address_space(1))) void*)g,
        (__attribute__((address_space(3))) void*)l, 16, 0, 0);
}

// ---- tiled transpose: W [K][N] f32 -> Wt [N][K] bf16 (K,N multiples of 32) -
__global__ __launch_bounds__(256) void k_transpose_bf16(
    const float* __restrict__ W, unsigned short* __restrict__ Wt, int K, int N) {
    __shared__ unsigned short t[32][33];
    int k0 = blockIdx.x * 32, n0 = blockIdx.y * 32;
    int tr = threadIdx.x >> 3;          // 0..31
    int tc = (threadIdx.x & 7) * 4;     // 0,4,...,28
    float4 v = *(const float4*)(W + (long)(k0 + tr) * N + n0 + tc);
    t[tr][tc + 0] = f2bf(v.x); t[tr][tc + 1] = f2bf(v.y);
    t[tr][tc + 2] = f2bf(v.z); t[tr][tc + 3] = f2bf(v.w);
    __syncthreads();
    ushort4v o = { t[tc + 0][tr], t[tc + 1][tr], t[tc + 2][tr], t[tc + 3][tr] };
    *(ushort4v*)(Wt + (long)(n0 + tr) * K + k0 + tc) = o;
}

// ---- wide-BN MFMA GEMM: C[M][N] = relu(A[M][K] @ Bt[N][K]^T + bias) -------
// BN = N (1D grid over 64-row m-tiles) -> A read from global ONCE.
// 256 threads = 4 waves (2m x 2n); wave tile 32 x N/2; BK = 32.
// Double-buffered LDS, one barrier per K-step, next-tile loads issued first.
// LDS rows are 64B (32 bf16); 16B granule g of row r stored at slot
// g ^ ((r>>1)&3)  -> every frag ds_read_b128 hits the 8 slots of the 128B
// bank window uniformly (2-way = free). Sources pre-swizzled for gload_lds.
// AF32: A is f32 in global, reg-staged + packed to bf16 (swizzled ds_write).
template <int K, int N, int WGPB, bool AF32, bool OUTBF16>
__global__ __launch_bounds__(256, WGPB) void k_gemm_bias_relu(
    const void* __restrict__ Av, const unsigned short* __restrict__ Bt,
    const float* __restrict__ bias, void* __restrict__ Cv, int M) {
    constexpr int NF = N / 32;           // n-frags per wave
    __shared__ unsigned short As[2][64 * 32];
    __shared__ unsigned short Bs[2][N * 32];
    int tid = threadIdx.x;
    int w = tid >> 6, l = tid & 63;
    int wm = w >> 1, wn = w & 1;
    int mBase = blockIdx.x * 64;

    const float* Af = (const float*)Av;
    const unsigned short* Ab = (const unsigned short*)Av;

    // AF32 reg-staging: thread owns 8 consecutive f32 of one row
    int arow = tid >> 2;                  // 0..63
    int aslot = (tid & 3) ^ ((arow >> 1) & 3);   // swizzled 16B slot
    long aRowG = mBase + arow; if (aRowG >= M) aRowG = M - 1;
    const float* aptr = AF32 ? (Af + aRowG * K + (tid & 3) * 8) : nullptr;

    auto stageB = [&](int b, int k0) {
#pragma unroll
        for (int o = 0; o < N / 64; ++o) {
            int rbase = (o * 4 + w) * 16;            // wave-uniform
            int row = rbase + (l >> 2);
            int gsrc = (l & 3) ^ ((row >> 1) & 3);   // pre-swizzled source
            gload_lds16(Bt + (long)row * K + k0 + gsrc * 8, &Bs[b][rbase * 32]);
        }
    };
    auto stageAbf = [&](int b, int k0) {
        int rbase = w * 16;
        int row = rbase + (l >> 2);
        int gsrc = (l & 3) ^ ((row >> 1) & 3);
        long gr = mBase + row; if (gr >= M) gr = M - 1;
        gload_lds16(Ab + gr * K + k0 + gsrc * 8, &As[b][rbase * 32]);
    };

    f32x4 acc[2][NF] = {};
    constexpr int NSTEP = K / 32;

    // ---- prologue: stage k0 = 0 into buffer 0 -----------------------------
    stageB(0, 0);
    if constexpr (AF32) {
        float4 f0 = *(const float4*)(aptr);
        float4 f1 = *(const float4*)(aptr + 4);
        uint4v p = { cvtpk(f0.x, f0.y), cvtpk(f0.z, f0.w),
                     cvtpk(f1.x, f1.y), cvtpk(f1.z, f1.w) };
        *(uint4v*)(&As[0][arow * 32 + aslot * 8]) = p;
    } else {
        stageAbf(0, 0);
    }
    __syncthreads();

    int s = 0;
    for (int step = 0; step < NSTEP; ++step, s ^= 1) {
        int nk = (step + 1) * 32;
        float4 f0, f1;
        if (nk < K) {                      // issue next-tile loads FIRST
            stageB(s ^ 1, nk);
            if constexpr (AF32) {
                f0 = *(const float4*)(aptr + nk);
                f1 = *(const float4*)(aptr + nk + 4);
            } else {
                stageAbf(s ^ 1, nk);
            }
        }
        // ---- compute current buffer (swizzled reads) ----------------------
        bf16x8 af[2];
#pragma unroll
        for (int m = 0; m < 2; ++m) {
            int ra = wm * 32 + m * 16 + (l & 15);
            int g = (l >> 4) ^ ((ra >> 1) & 3);
            af[m] = *(const bf16x8*)(&As[s][ra * 32 + g * 8]);
        }
#pragma unroll
        for (int n = 0; n < NF; ++n) {
            int rb = wn * (N / 2) + n * 16 + (l & 15);
            int g = (l >> 4) ^ ((rb >> 1) & 3);
            bf16x8 bfr = *(const bf16x8*)(&Bs[s][rb * 32 + g * 8]);
#pragma unroll
            for (int m = 0; m < 2; ++m)
                acc[m][n] = __builtin_amdgcn_mfma_f32_16x16x32_bf16(
                    af[m], bfr, acc[m][n], 0, 0, 0);
        }
        if constexpr (AF32) {
            if (nk < K) {                    // write next A after MFMAs
                uint4v p = { cvtpk(f0.x, f0.y), cvtpk(f0.z, f0.w),
                             cvtpk(f1.x, f1.y), cvtpk(f1.z, f1.w) };
                *(uint4v*)(&As[s ^ 1][arow * 32 + aslot * 8]) = p;
            }
        }
        __syncthreads();
    }

    // ---- epilogue: row=(l>>4)*4+r, col=l&15 (HW-verified) -----------------
#pragma unroll
    for (int m = 0; m < 2; ++m) {
        int row = mBase + wm * 32 + m * 16 + (l >> 4) * 4;
#pragma unroll
        for (int n = 0; n < NF; ++n) {
            int colg = wn * (N / 2) + n * 16 + (l & 15);
            float bv = bias[colg];
#pragma unroll
            for (int r = 0; r < 4; ++r) {
                if (row + r < M) {
                    float v = fmaxf(acc[m][n][r] + bv, 0.f);
                    if constexpr (OUTBF16)
                        ((unsigned short*)Cv)[(long)(row + r) * N + colg] = f2bf(v);
                    else
                        ((float*)Cv)[(long)(row + r) * N + colg] = v;
                }
            }
        }
    }
}

// ---- CSR build ------------------------------------------------------------
__global__ void k_csr_init(int* __restrict__ cnt, int* __restrict__ fill, int n) {
    int i = blockIdx.x * blockDim.x + threadIdx.x;
    if (i < n) { cnt[i] = 1; fill[i] = 0; }   // 1 = self loop
}

__global__ void k_csr_count(const int* __restrict__ ei, int* __restrict__ cnt, int E) {
    int e = blockIdx.x * blockDim.x + threadIdx.x;
    if (e < E) atomicAdd(&cnt[ei[E + e]], 1);   // dst row
}

// hierarchical exclusive scan: phase 1 (per-1024-chunk scan + chunk total)
__global__ __launch_bounds__(1024) void k_scan1(const int* __restrict__ cnt,
                                                int* __restrict__ rowp,
                                                int* __restrict__ bsum, int n) {
    __shared__ int wsum[16];
    int b = blockIdx.x, t = threadIdx.x, lane = t & 63, w = t >> 6;
    int i = b * 1024 + t;
    int v = (i < n) ? cnt[i] : 0;
    int x = v;
#pragma unroll
    for (int off = 1; off < 64; off <<= 1) {
        int y = __shfl_up(x, off, 64);
        if (lane >= off) x += y;
    }
    if (lane == 63) wsum[w] = x;
    __syncthreads();
    if (t < 16) {
        int s = wsum[t];
#pragma unroll
        for (int off = 1; off < 16; off <<= 1) {
            int y = __shfl_up(s, off, 64);
            if (t >= off) s += y;
        }
        wsum[t] = s;
    }
    __syncthreads();
    int wo = w ? wsum[w - 1] : 0;
    if (i < n) rowp[i] = wo + x - v;            // chunk-local exclusive
    if (t == 0) bsum[b] = wsum[15];             // chunk total
}

// phase 2: exclusive scan of <=64 chunk totals (single wave)
__global__ __launch_bounds__(64) void k_scan2(int* __restrict__ bsum, int nb) {
    int lane = threadIdx.x;
    int v = (lane < nb) ? bsum[lane] : 0;
    int x = v;
#pragma unroll
    for (int off = 1; off < 64; off <<= 1) {
        int y = __shfl_up(x, off, 64);
        if (lane >= off) x += y;
    }
    int total = __shfl(x, nb - 1, 64);
    if (lane < nb) bsum[lane] = x - v;          // exclusive
    if (lane == 0) bsum[nb] = total;
}

// phase 3: add chunk offsets; write rowp[n] = total
__global__ __launch_bounds__(1024) void k_scan3(const int* __restrict__ bsum,
                                                int* __restrict__ rowp, int n, int nb) {
    int i = blockIdx.x * 1024 + threadIdx.x;
    if (i < n) rowp[i] += bsum[i >> 10];
    else if (i == n) rowp[n] = bsum[nb];
}

__global__ void k_csr_fill(const int* __restrict__ ei, const int* __restrict__ rowp,
                           int* __restrict__ fill, int* __restrict__ col, int E, int n) {
    int idx = blockIdx.x * blockDim.x + threadIdx.x;
    if (idx < E) {
        int d = ei[E + idx];
        int s = ei[idx];
        int pos = atomicAdd(&fill[d], 1);
        col[rowp[d] + pos] = s;
    } else if (idx < E + n) {
        int nd = idx - E;
        int pos = atomicAdd(&fill[nd], 1);
        col[rowp[nd] + pos] = nd;   // self loop
    }
}

// ---- row inverse L2 norm, bf16 rows (H=512) --------------------------------
__global__ __launch_bounds__(256) void k_norm_bf16(const unsigned short* __restrict__ h,
                                                   float* __restrict__ invn, int n) {
    int row = blockIdx.x * 4 + (threadIdx.x >> 6);
    int lane = threadIdx.x & 63;
    if (row >= n) return;
    ushort8 v = *(const ushort8*)(h + (long)row * 512 + lane * 8);
    float s = 0.f;
#pragma unroll
    for (int e = 0; e < 8; ++e) { float f = bf2f(v[e]); s += f * f; }
#pragma unroll
    for (int off = 32; off; off >>= 1) s += __shfl_xor(s, off, 64);
    if (lane == 0) invn[row] = 1.f / fmaxf(sqrtf(s), 1e-12f);
}

// ---- AGNN propagation: bf16 rows, one wave per dst, single-pass -----------
// Optionally fuses the inv-L2-norm of the OUTPUT row (for the next prop).
__global__ __launch_bounds__(256) void k_agnn(
    const unsigned short* __restrict__ h, const float* __restrict__ invn,
    const int* __restrict__ rowp, const int* __restrict__ col,
    const float* __restrict__ beta_ptr, unsigned short* __restrict__ out,
    float* __restrict__ invn_out, int nNodes) {
    int dst = blockIdx.x * 4 + (threadIdx.x >> 6);
    int lane = threadIdx.x & 63;
    if (dst >= nNodes) return;
    float beta = beta_ptr ? beta_ptr[0] : 1.0f;
    ushort8 hdv = *(const ushort8*)(h + (long)dst * 512 + lane * 8);
    float hd[8];
#pragma unroll
    for (int e = 0; e < 8; ++e) hd[e] = bf2f(hdv[e]);
    float coef = beta * invn[dst];
    int s0 = rowp[dst], s1 = rowp[dst + 1];

    float m = -1e30f, ssum = 0.f;
    float acc[8] = {0.f, 0.f, 0.f, 0.f, 0.f, 0.f, 0.f, 0.f};

    for (int base = s0; base < s1; base += 64) {
        int cnt = min(s1 - base, 64);
        int gi = base + lane; if (gi >= s1) gi = s1 - 1;
        int idxl = col[gi];              // batch of up to 64 edge indices
        float vinl = invn[idxl];         // batch of src inv-norms
        int src0 = __shfl(idxl, 0, 64);
        ushort8 nxt = *(const ushort8*)(h + (long)src0 * 512 + lane * 8);
        for (int j = 0; j < cnt; ++j) {
            ushort8 cur = nxt;
            if (j + 1 < cnt) {
                int sn = __shfl(idxl, j + 1, 64);
                nxt = *(const ushort8*)(h + (long)sn * 512 + lane * 8);  // prefetch
            }
            float a[8];
#pragma unroll
            for (int e = 0; e < 8; ++e) a[e] = bf2f(cur[e]);
            float p = a[0] * hd[0] + a[1] * hd[1] + a[2] * hd[2] + a[3] * hd[3] +
                      a[4] * hd[4] + a[5] * hd[5] + a[6] * hd[6] + a[7] * hd[7];
#pragma unroll
            for (int off = 32; off; off >>= 1) p += __shfl_xor(p, off, 64);
            float alpha = coef * __shfl(vinl, j, 64) * p;
            if (alpha > m) {             // wave-uniform (alpha fully reduced)
                float sc = __expf(m - alpha);
                ssum *= sc;
#pragma unroll
                for (int e = 0; e < 8; ++e) acc[e] *= sc;
                m = alpha;
            }
            float wgt = __expf(alpha - m);
            ssum += wgt;
#pragma unroll
            for (int e = 0; e < 8; ++e) acc[e] += wgt * a[e];
        }
    }
    float inv_s = 1.f / ssum;
#pragma unroll
    for (int e = 0; e < 8; ++e) acc[e] *= inv_s;

    uint4v o = { cvtpk(acc[0], acc[1]), cvtpk(acc[2], acc[3]),
                 cvtpk(acc[4], acc[5]), cvtpk(acc[6], acc[7]) };
    *(uint4v*)(out + (long)dst * 512 + lane * 8) = o;

    if (invn_out) {                      // fused output norm (feeds next prop)
        float s = 0.f;
#pragma unroll
        for (int e = 0; e < 8; ++e) s += acc[e] * acc[e];
#pragma unroll
        for (int off = 32; off; off >>= 1) s += __shfl_xor(s, off, 64);
        if (lane == 0) invn_out[dst] = 1.f / fmaxf(sqrtf(s), 1e-12f);
    }
}

// ---- graph boundaries in sorted batch -------------------------------------
__global__ void k_bounds(const int* __restrict__ batch, int* __restrict__ starts,
                         int n, int G) {
    int g = blockIdx.x * blockDim.x + threadIdx.x;
    if (g > G) return;
    int lo = 0, hi = n;
    while (lo < hi) {
        int mid = (lo + hi) >> 1;
        if (batch[mid] < g) lo = mid + 1; else hi = mid;
    }
    starts[g] = lo;
}

// ---- per-graph max/mean pool (H2=256) -------------------------------------
__global__ __launch_bounds__(256) void k_pool(const float* __restrict__ h3,
                                              const int* __restrict__ starts,
                                              float* __restrict__ pooled) {
    int g = blockIdx.x;
    int t = threadIdx.x;
    int s = starts[g], e = starts[g + 1];
    float mx = -3.402823466e38f, sm = 0.f;
    int r = s;
    for (; r + 4 <= e; r += 4) {          // ILP unroll
        float v0 = h3[(long)(r + 0) * 256 + t];
        float v1 = h3[(long)(r + 1) * 256 + t];
        float v2 = h3[(long)(r + 2) * 256 + t];
        float v3 = h3[(long)(r + 3) * 256 + t];
        mx = fmaxf(mx, fmaxf(fmaxf(v0, v1), fmaxf(v2, v3)));
        sm += (v0 + v1) + (v2 + v3);
    }
    for (; r < e; ++r) {
        float v = h3[(long)r * 256 + t];
        mx = fmaxf(mx, v); sm += v;
    }
    float cnt = fmaxf((float)(e - s), 1.f);
    pooled[g * 512 + t] = mx;
    pooled[g * 512 + 256 + t] = sm / cnt;
}

// ---- final tiny GEMM: out[G][C] = pooled[G][512] @ W3[512][C] + b3 --------
__global__ __launch_bounds__(64) void k_final(const float* __restrict__ pooled,
                                              const float* __restrict__ W3,
                                              const float* __restrict__ b3,
                                              float* __restrict__ out, int C) {
    int g = blockIdx.x;
    int lane = threadIdx.x;
    for (int c = 0; c < C; c++) {
        float p = 0.f;
        for (int k = lane; k < 512; k += 64) p += pooled[g * 512 + k] * W3[k * C + c];
#pragma unroll
        for (int off = 32; off; off >>= 1) p += __shfl_xor(p, off, 64);
        if (lane == 0) out[g * C + c] = p + b3[c];
    }
}

// ---------------------------------------------------------------------------
extern "C" void kernel_launch(void* const* d_in, const int* in_sizes, int n_in,
                              void* d_out, int out_size, void* d_ws, size_t ws_size,
                              hipStream_t stream) {
    const float* x     = (const float*)d_in[0];
    const int*   ei    = (const int*)d_in[1];
    const int*   batch = (const int*)d_in[2];
    const float* W1    = (const float*)d_in[3];
    const float* b1    = (const float*)d_in[4];
    const float* beta2 = (const float*)d_in[5];
    const float* W2    = (const float*)d_in[6];
    const float* b2    = (const float*)d_in[7];
    const float* W3    = (const float*)d_in[8];
    const float* b3    = (const float*)d_in[9];
    float* out = (float*)d_out;

    const int N = in_sizes[2];          // 30000
    const int E = in_sizes[1] / 2;      // 480000
    const int F_IN = in_sizes[0] / N;   // 1280
    const int H = in_sizes[4];          // 512
    const int H2 = in_sizes[7];         // 256
    const int C = in_sizes[9];          // 10
    const int G = out_size / C;         // 64

    char* ws = (char*)d_ws;
    unsigned short* H1B = (unsigned short*)(ws + 0);            // 30.72 MB bf16
    unsigned short* HPB = (unsigned short*)(ws + 31000000L);    // 30.72 MB bf16
    unsigned short* H2B = (unsigned short*)(ws + 62000000L);    // 30.72 MB bf16
    float*          H3  = (float*)(ws + 0);                     // 61.44 MB f32 (over H1B/HPB, both dead)
    unsigned short* W1T = (unsigned short*)(ws + 93000000L);    // 1.31 MB
    unsigned short* W2T = (unsigned short*)(ws + 94500000L);    // 0.26 MB
    float* INVN_A = (float*)(ws + 95000000L);                   // 120 KB
    float* INVN_B = (float*)(ws + 95200000L);                   // 120 KB
    int*   CNT    = (int*)(ws + 95400000L);
    int*   FILL   = (int*)(ws + 95600000L);
    int*   ROWP   = (int*)(ws + 95800000L);
    int*   COL    = (int*)(ws + 96000000L);                     // 2.04 MB
    int*   BSUM   = (int*)(ws + 98100000L);
    int*   START  = (int*)(ws + 98110000L);
    float* POOLED = (float*)(ws + 98120000L);                   // 131 KB

    // 1. weight transposes (f32 -> bf16 [N][K])
    { dim3 g1(F_IN / 32, H / 32); k_transpose_bf16<<<g1, 256, 0, stream>>>(W1, W1T, F_IN, H); }
    { dim3 g2(H / 32, H2 / 32);   k_transpose_bf16<<<g2, 256, 0, stream>>>(W2, W2T, H, H2); }

    // 2. CSR (incoming edges + self loops)
    int nb = (N + 1023) / 1024;   // 30
    k_csr_init<<<(N + 255) / 256, 256, 0, stream>>>(CNT, FILL, N);
    k_csr_count<<<(E + 255) / 256, 256, 0, stream>>>(ei, CNT, E);
    k_scan1<<<nb, 1024, 0, stream>>>(CNT, ROWP, BSUM, N);
    k_scan2<<<1, 64, 0, stream>>>(BSUM, nb);
    k_scan3<<<(N + 1 + 1023) / 1024, 1024, 0, stream>>>(BSUM, ROWP, N, nb);
    k_csr_fill<<<(E + N + 255) / 256, 256, 0, stream>>>(ei, ROWP, FILL, COL, E, N);

    // 3. GEMM1: H1B = bf16(relu(x @ W1 + b1))  [N,512]; BN=512 read-once A
    k_gemm_bias_relu<1280, 512, 2, true, true>
        <<<(N + 63) / 64, 256, 0, stream>>>(x, W1T, b1, H1B, N);

    // 4. prop1 (beta=1): HPB = AGNN(H1B), fused invn of HPB -> INVN_B
    k_norm_bf16<<<(N + 3) / 4, 256, 0, stream>>>(H1B, INVN_A, N);
    k_agnn<<<(N + 3) / 4, 256, 0, stream>>>(H1B, INVN_A, ROWP, COL, nullptr, HPB, INVN_B, N);

    // 5. prop2 (beta=beta2): H2B = AGNN(HPB)
    k_agnn<<<(N + 3) / 4, 256, 0, stream>>>(HPB, INVN_B, ROWP, COL, beta2, H2B, nullptr, N);

    // 6. GEMM2: H3 = relu(H2B @ W2 + b2)  [N,256] f32; BN=256 read-once A
    k_gemm_bias_relu<512, 256, 3, false, false>
        <<<(N + 63) / 64, 256, 0, stream>>>(H2B, W2T, b2, H3, N);

    // 7. pool + final linear
    k_bounds<<<1, 128, 0, stream>>>(batch, START, N, G);
    k_pool<<<G, 256, 0, stream>>>(H3, START, POOLED);
    k_final<<<G, 64, 0, stream>>>(POOLED, W3, b3, out, C);
}

// Round 6
// 376.167 us; speedup vs baseline: 3.5034x; 1.0504x over previous
//
#include <hip/hip_runtime.h>
#include <hip/hip_bf16.h>
#include <cstdint>

// ---------------------------------------------------------------------------
// Model: h=relu(x@W1+b1); h=AGNN(h,beta=1); h=AGNN(h,beta2); h=relu(h@W2+b2);
//        out = concat(segmax(h,batch), segmean(h,batch)) @ W3 + b3
// N=30000, E=480000, F_IN=1280, H=512, H2=256, G=64, C=10
// bf16 rows through propagation; 128x256 8-wave MFMA GEMMs (2 blocks/CU,
// 16 waves/CU); XOR-swizzled LDS; DPP wave reduction in AGNN.
// ---------------------------------------------------------------------------

typedef __attribute__((ext_vector_type(8))) short bf16x8;
typedef __attribute__((ext_vector_type(4))) float f32x4;
typedef __attribute__((ext_vector_type(8))) unsigned short ushort8;
typedef __attribute__((ext_vector_type(4))) unsigned short ushort4v;
typedef __attribute__((ext_vector_type(4))) unsigned int uint4v;

__device__ inline unsigned short f2bf(float f) {
    unsigned int u = __float_as_uint(f);
    u += 0x7FFFu + ((u >> 16) & 1u);   // RNE
    return (unsigned short)(u >> 16);
}

__device__ __forceinline__ float bf2f(unsigned short u) {
    return __uint_as_float(((unsigned int)u) << 16);
}

// packed f32x2 -> bf16x2 (RNE), single HW instruction on gfx950
__device__ __forceinline__ unsigned int cvtpk(float lo, float hi) {
    unsigned int r;
    asm("v_cvt_pk_bf16_f32 %0, %1, %2" : "=v"(r) : "v"(lo), "v"(hi));
    return r;
}

__device__ __forceinline__ void gload_lds16(const void* g, void* l) {
    __builtin_amdgcn_global_load_lds(
        (const __attribute__((address_space(1))) void*)g,
        (__attribute__((address_space(3))) void*)l, 16, 0, 0);
}

// ---- wave64 sum via DPP (VALU pipe, no ds_bpermute). Result uniform. ------
__device__ __forceinline__ float wave_sum_dpp(float p) {
    int t;
    t = __builtin_amdgcn_update_dpp(0, __float_as_int(p), 0xB1, 0xf, 0xf, true);  // quad_perm [1,0,3,2]
    p += __int_as_float(t);
    t = __builtin_amdgcn_update_dpp(0, __float_as_int(p), 0x4E, 0xf, 0xf, true);  // quad_perm [2,3,0,1]
    p += __int_as_float(t);
    t = __builtin_amdgcn_update_dpp(0, __float_as_int(p), 0x141, 0xf, 0xf, true); // row_half_mirror
    p += __int_as_float(t);
    t = __builtin_amdgcn_update_dpp(0, __float_as_int(p), 0x140, 0xf, 0xf, true); // row_mirror
    p += __int_as_float(t);
    t = __builtin_amdgcn_update_dpp(0, __float_as_int(p), 0x142, 0xf, 0xf, true); // row_bcast15
    p += __int_as_float(t);
    t = __builtin_amdgcn_update_dpp(0, __float_as_int(p), 0x143, 0xf, 0xf, true); // row_bcast31
    p += __int_as_float(t);
    return __int_as_float(__builtin_amdgcn_readlane(__float_as_int(p), 63));
}

// ---- tiled transpose: W [K][N] f32 -> Wt [N][K] bf16 (K,N multiples of 32) -
__global__ __launch_bounds__(256) void k_transpose_bf16(
    const float* __restrict__ W, unsigned short* __restrict__ Wt, int K, int N) {
    __shared__ unsigned short t[32][33];
    int k0 = blockIdx.x * 32, n0 = blockIdx.y * 32;
    int tr = threadIdx.x >> 3;          // 0..31
    int tc = (threadIdx.x & 7) * 4;     // 0,4,...,28
    float4 v = *(const float4*)(W + (long)(k0 + tr) * N + n0 + tc);
    t[tr][tc + 0] = f2bf(v.x); t[tr][tc + 1] = f2bf(v.y);
    t[tr][tc + 2] = f2bf(v.z); t[tr][tc + 3] = f2bf(v.w);
    __syncthreads();
    ushort4v o = { t[tc + 0][tr], t[tc + 1][tr], t[tc + 2][tr], t[tc + 3][tr] };
    *(ushort4v*)(Wt + (long)(n0 + tr) * K + k0 + tc) = o;
}

// ---- MFMA GEMM: C[M][N] = relu(A[M][K] @ Bt[N][K]^T + bias) ---------------
// Block tile 128 x BN (BN=256), 512 threads = 8 waves (2m x 4n), wave tile
// 64x64 (acc[4][4]), BK=32. LDS 48 KB double-buffered -> 2 blocks/CU =
// 16 waves/CU (VGPR cap 128 via launch_bounds). One barrier per K-step;
// next-tile loads issued before the current tile's MFMAs.
// LDS rows 64B; 16B granule g of row r at slot g ^ ((r>>1)&3) (conflict-free,
// applied on both sides: pre-swizzled global source / swizzled ds addrs).
// AF32: A is f32 in global, reg-staged + packed to bf16 (swizzled ds_write).
template <int K, int BN, int NOUT, bool AF32, bool OUTBF16>
__global__ __launch_bounds__(512, 4) void k_gemm_bias_relu(
    const void* __restrict__ Av, const unsigned short* __restrict__ Bt,
    const float* __restrict__ bias, void* __restrict__ Cv, int M) {
    __shared__ unsigned short As[2][128 * 32];
    __shared__ unsigned short Bs[2][BN * 32];
    int tid = threadIdx.x;
    int w = tid >> 6, l = tid & 63;
    int wm = w >> 2, wn = w & 3;
    int mBase = blockIdx.x * 128;
    int nBase = blockIdx.y * BN;

    const float* Af = (const float*)Av;
    const unsigned short* Ab = (const unsigned short*)Av;

    // AF32 reg-staging: thread owns 8 consecutive f32 of one row (4 thr/row)
    int arow = tid >> 2;                          // 0..127
    int aslot = (tid & 3) ^ ((arow >> 1) & 3);    // swizzled 16B slot
    long aRowG = mBase + arow; if (aRowG >= M) aRowG = M - 1;
    const float* aptr = AF32 ? (Af + aRowG * K + (tid & 3) * 8) : nullptr;

    auto stageB = [&](int b, int k0) {
#pragma unroll
        for (int o = 0; o < BN / 128; ++o) {
            int rbase = (w * (BN / 128) + o) * 16;       // wave-uniform
            int row = rbase + (l >> 2);                  // local B row
            int gsrc = (l & 3) ^ ((row >> 1) & 3);       // pre-swizzled src
            gload_lds16(Bt + (long)(nBase + row) * K + k0 + gsrc * 8,
                        &Bs[b][rbase * 32]);
        }
    };
    auto stageAbf = [&](int b, int k0) {
        int rbase = w * 16;
        int row = rbase + (l >> 2);
        int gsrc = (l & 3) ^ ((row >> 1) & 3);
        long gr = mBase + row; if (gr >= M) gr = M - 1;
        gload_lds16(Ab + gr * K + k0 + gsrc * 8, &As[b][rbase * 32]);
    };

    f32x4 acc[4][4] = {};
    constexpr int NSTEP = K / 32;

    // ---- prologue: stage k0 = 0 into buffer 0 -----------------------------
    stageB(0, 0);
    if constexpr (AF32) {
        float4 f0 = *(const float4*)(aptr);
        float4 f1 = *(const float4*)(aptr + 4);
        uint4v p = { cvtpk(f0.x, f0.y), cvtpk(f0.z, f0.w),
                     cvtpk(f1.x, f1.y), cvtpk(f1.z, f1.w) };
        *(uint4v*)(&As[0][arow * 32 + aslot * 8]) = p;
    } else {
        stageAbf(0, 0);
    }
    __syncthreads();

    int s = 0;
    for (int step = 0; step < NSTEP; ++step, s ^= 1) {
        int nk = (step + 1) * 32;
        float4 f0, f1;
        if (nk < K) {                      // issue next-tile loads FIRST
            stageB(s ^ 1, nk);
            if constexpr (AF32) {
                f0 = *(const float4*)(aptr + nk);
                f1 = *(const float4*)(aptr + nk + 4);
            } else {
                stageAbf(s ^ 1, nk);
            }
        }
        // ---- compute current buffer (swizzled reads) ----------------------
        bf16x8 af[4];
#pragma unroll
        for (int m = 0; m < 4; ++m) {
            int ra = wm * 64 + m * 16 + (l & 15);
            int g = (l >> 4) ^ ((ra >> 1) & 3);
            af[m] = *(const bf16x8*)(&As[s][ra * 32 + g * 8]);
        }
#pragma unroll
        for (int n = 0; n < 4; ++n) {
            int rb = wn * 64 + n * 16 + (l & 15);
            int g = (l >> 4) ^ ((rb >> 1) & 3);
            bf16x8 bfr = *(const bf16x8*)(&Bs[s][rb * 32 + g * 8]);
#pragma unroll
            for (int m = 0; m < 4; ++m)
                acc[m][n] = __builtin_amdgcn_mfma_f32_16x16x32_bf16(
                    af[m], bfr, acc[m][n], 0, 0, 0);
        }
        if constexpr (AF32) {
            if (nk < K) {                    // write next A after MFMAs
                uint4v p = { cvtpk(f0.x, f0.y), cvtpk(f0.z, f0.w),
                             cvtpk(f1.x, f1.y), cvtpk(f1.z, f1.w) };
                *(uint4v*)(&As[s ^ 1][arow * 32 + aslot * 8]) = p;
            }
        }
        __syncthreads();
    }

    // ---- epilogue: row=(l>>4)*4+r, col=l&15 (HW-verified) -----------------
#pragma unroll
    for (int m = 0; m < 4; ++m) {
        int row = mBase + wm * 64 + m * 16 + (l >> 4) * 4;
#pragma unroll
        for (int n = 0; n < 4; ++n) {
            int colg = nBase + wn * 64 + n * 16 + (l & 15);
            float bv = bias[colg];
#pragma unroll
            for (int r = 0; r < 4; ++r) {
                if (row + r < M) {
                    float v = fmaxf(acc[m][n][r] + bv, 0.f);
                    if constexpr (OUTBF16)
                        ((unsigned short*)Cv)[(long)(row + r) * NOUT + colg] = f2bf(v);
                    else
                        ((float*)Cv)[(long)(row + r) * NOUT + colg] = v;
                }
            }
        }
    }
}

// ---- CSR build ------------------------------------------------------------
__global__ void k_csr_init(int* __restrict__ cnt, int* __restrict__ fill, int n) {
    int i = blockIdx.x * blockDim.x + threadIdx.x;
    if (i < n) { cnt[i] = 1; fill[i] = 0; }   // 1 = self loop
}

__global__ void k_csr_count(const int* __restrict__ ei, int* __restrict__ cnt, int E) {
    int e = blockIdx.x * blockDim.x + threadIdx.x;
    if (e < E) atomicAdd(&cnt[ei[E + e]], 1);   // dst row
}

// hierarchical exclusive scan: phase 1 (per-1024-chunk scan + chunk total)
__global__ __launch_bounds__(1024) void k_scan1(const int* __restrict__ cnt,
                                                int* __restrict__ rowp,
                                                int* __restrict__ bsum, int n) {
    __shared__ int wsum[16];
    int b = blockIdx.x, t = threadIdx.x, lane = t & 63, w = t >> 6;
    int i = b * 1024 + t;
    int v = (i < n) ? cnt[i] : 0;
    int x = v;
#pragma unroll
    for (int off = 1; off < 64; off <<= 1) {
        int y = __shfl_up(x, off, 64);
        if (lane >= off) x += y;
    }
    if (lane == 63) wsum[w] = x;
    __syncthreads();
    if (t < 16) {
        int s = wsum[t];
#pragma unroll
        for (int off = 1; off < 16; off <<= 1) {
            int y = __shfl_up(s, off, 64);
            if (t >= off) s += y;
        }
        wsum[t] = s;
    }
    __syncthreads();
    int wo = w ? wsum[w - 1] : 0;
    if (i < n) rowp[i] = wo + x - v;            // chunk-local exclusive
    if (t == 0) bsum[b] = wsum[15];             // chunk total
}

// phase 2: exclusive scan of <=64 chunk totals (single wave)
__global__ __launch_bounds__(64) void k_scan2(int* __restrict__ bsum, int nb) {
    int lane = threadIdx.x;
    int v = (lane < nb) ? bsum[lane] : 0;
    int x = v;
#pragma unroll
    for (int off = 1; off < 64; off <<= 1) {
        int y = __shfl_up(x, off, 64);
        if (lane >= off) x += y;
    }
    int total = __shfl(x, nb - 1, 64);
    if (lane < nb) bsum[lane] = x - v;          // exclusive
    if (lane == 0) bsum[nb] = total;
}

// phase 3: add chunk offsets; write rowp[n] = total
__global__ __launch_bounds__(1024) void k_scan3(const int* __restrict__ bsum,
                                                int* __restrict__ rowp, int n, int nb) {
    int i = blockIdx.x * 1024 + threadIdx.x;
    if (i < n) rowp[i] += bsum[i >> 10];
    else if (i == n) rowp[n] = bsum[nb];
}

__global__ void k_csr_fill(const int* __restrict__ ei, const int* __restrict__ rowp,
                           int* __restrict__ fill, int* __restrict__ col, int E, int n) {
    int idx = blockIdx.x * blockDim.x + threadIdx.x;
    if (idx < E) {
        int d = ei[E + idx];
        int s = ei[idx];
        int pos = atomicAdd(&fill[d], 1);
        col[rowp[d] + pos] = s;
    } else if (idx < E + n) {
        int nd = idx - E;
        int pos = atomicAdd(&fill[nd], 1);
        col[rowp[nd] + pos] = nd;   // self loop
    }
}

// ---- row inverse L2 norm, bf16 rows (H=512) --------------------------------
__global__ __launch_bounds__(256) void k_norm_bf16(const unsigned short* __restrict__ h,
                                                   float* __restrict__ invn, int n) {
    int row = blockIdx.x * 4 + (threadIdx.x >> 6);
    int lane = threadIdx.x & 63;
    if (row >= n) return;
    ushort8 v = *(const ushort8*)(h + (long)row * 512 + lane * 8);
    float s = 0.f;
#pragma unroll
    for (int e = 0; e < 8; ++e) { float f = bf2f(v[e]); s += f * f; }
    s = wave_sum_dpp(s);
    if (lane == 0) invn[row] = 1.f / fmaxf(sqrtf(s), 1e-12f);
}

// ---- AGNN propagation: bf16 rows, one wave per dst, single-pass -----------
// DPP wave reduce (no ds_bpermute in the per-edge chain); readlane broadcasts.
// Optionally fuses the inv-L2-norm of the OUTPUT row (for the next prop).
__global__ __launch_bounds__(256) void k_agnn(
    const unsigned short* __restrict__ h, const float* __restrict__ invn,
    const int* __restrict__ rowp, const int* __restrict__ col,
    const float* __restrict__ beta_ptr, unsigned short* __restrict__ out,
    float* __restrict__ invn_out, int nNodes) {
    int dst = blockIdx.x * 4 + (threadIdx.x >> 6);
    int lane = threadIdx.x & 63;
    if (dst >= nNodes) return;
    float beta = beta_ptr ? beta_ptr[0] : 1.0f;
    ushort8 hdv = *(const ushort8*)(h + (long)dst * 512 + lane * 8);
    float hd[8];
#pragma unroll
    for (int e = 0; e < 8; ++e) hd[e] = bf2f(hdv[e]);
    float coef = beta * invn[dst];
    int s0 = rowp[dst], s1 = rowp[dst + 1];

    float m = -1e30f, ssum = 0.f;
    float acc[8] = {0.f, 0.f, 0.f, 0.f, 0.f, 0.f, 0.f, 0.f};

    for (int base = s0; base < s1; base += 64) {
        int cnt = min(s1 - base, 64);
        int gi = base + lane; if (gi >= s1) gi = s1 - 1;
        int idxl = col[gi];              // batch of up to 64 edge indices
        float vinl = invn[idxl];         // batch of src inv-norms
        int src0 = __builtin_amdgcn_readlane(idxl, 0);
        ushort8 nxt = *(const ushort8*)(h + (long)src0 * 512 + lane * 8);
        for (int j = 0; j < cnt; ++j) {
            ushort8 cur = nxt;
            if (j + 1 < cnt) {
                int sn = __builtin_amdgcn_readlane(idxl, j + 1);
                nxt = *(const ushort8*)(h + (long)sn * 512 + lane * 8);  // prefetch
            }
            float a[8];
#pragma unroll
            for (int e = 0; e < 8; ++e) a[e] = bf2f(cur[e]);
            float p = a[0] * hd[0] + a[1] * hd[1] + a[2] * hd[2] + a[3] * hd[3] +
                      a[4] * hd[4] + a[5] * hd[5] + a[6] * hd[6] + a[7] * hd[7];
            p = wave_sum_dpp(p);         // uniform across wave
            float vin_j = __int_as_float(
                __builtin_amdgcn_readlane(__float_as_int(vinl), j));
            float alpha = coef * vin_j * p;
            if (alpha > m) {             // wave-uniform
                float sc = __expf(m - alpha);
                ssum *= sc;
#pragma unroll
                for (int e = 0; e < 8; ++e) acc[e] *= sc;
                m = alpha;
            }
            float wgt = __expf(alpha - m);
            ssum += wgt;
#pragma unroll
            for (int e = 0; e < 8; ++e) acc[e] += wgt * a[e];
        }
    }
    float inv_s = 1.f / ssum;
#pragma unroll
    for (int e = 0; e < 8; ++e) acc[e] *= inv_s;

    uint4v o = { cvtpk(acc[0], acc[1]), cvtpk(acc[2], acc[3]),
                 cvtpk(acc[4], acc[5]), cvtpk(acc[6], acc[7]) };
    *(uint4v*)(out + (long)dst * 512 + lane * 8) = o;

    if (invn_out) {                      // fused output norm (feeds next prop)
        float s = 0.f;
#pragma unroll
        for (int e = 0; e < 8; ++e) s += acc[e] * acc[e];
        s = wave_sum_dpp(s);
        if (lane == 0) invn_out[dst] = 1.f / fmaxf(sqrtf(s), 1e-12f);
    }
}

// ---- graph boundaries in sorted batch -------------------------------------
__global__ void k_bounds(const int* __restrict__ batch, int* __restrict__ starts,
                         int n, int G) {
    int g = blockIdx.x * blockDim.x + threadIdx.x;
    if (g > G) return;
    int lo = 0, hi = n;
    while (lo < hi) {
        int mid = (lo + hi) >> 1;
        if (batch[mid] < g) lo = mid + 1; else hi = mid;
    }
    starts[g] = lo;
}

// ---- per-graph max/mean pool (H2=256) -------------------------------------
__global__ __launch_bounds__(256) void k_pool(const float* __restrict__ h3,
                                              const int* __restrict__ starts,
                                              float* __restrict__ pooled) {
    int g = blockIdx.x;
    int t = threadIdx.x;
    int s = starts[g], e = starts[g + 1];
    float mx = -3.402823466e38f, sm = 0.f;
    int r = s;
    for (; r + 4 <= e; r += 4) {          // ILP unroll
        float v0 = h3[(long)(r + 0) * 256 + t];
        float v1 = h3[(long)(r + 1) * 256 + t];
        float v2 = h3[(long)(r + 2) * 256 + t];
        float v3 = h3[(long)(r + 3) * 256 + t];
        mx = fmaxf(mx, fmaxf(fmaxf(v0, v1), fmaxf(v2, v3)));
        sm += (v0 + v1) + (v2 + v3);
    }
    for (; r < e; ++r) {
        float v = h3[(long)r * 256 + t];
        mx = fmaxf(mx, v); sm += v;
    }
    float cnt = fmaxf((float)(e - s), 1.f);
    pooled[g * 512 + t] = mx;
    pooled[g * 512 + 256 + t] = sm / cnt;
}

// ---- final tiny GEMM: out[G][C] = pooled[G][512] @ W3[512][C] + b3 --------
__global__ __launch_bounds__(64) void k_final(const float* __restrict__ pooled,
                                              const float* __restrict__ W3,
                                              const float* __restrict__ b3,
                                              float* __restrict__ out, int C) {
    int g = blockIdx.x;
    int lane = threadIdx.x;
    for (int c = 0; c < C; c++) {
        float p = 0.f;
        for (int k = lane; k < 512; k += 64) p += pooled[g * 512 + k] * W3[k * C + c];
#pragma unroll
        for (int off = 32; off; off >>= 1) p += __shfl_xor(p, off, 64);
        if (lane == 0) out[g * C + c] = p + b3[c];
    }
}

// ---------------------------------------------------------------------------
extern "C" void kernel_launch(void* const* d_in, const int* in_sizes, int n_in,
                              void* d_out, int out_size, void* d_ws, size_t ws_size,
                              hipStream_t stream) {
    const float* x     = (const float*)d_in[0];
    const int*   ei    = (const int*)d_in[1];
    const int*   batch = (const int*)d_in[2];
    const float* W1    = (const float*)d_in[3];
    const float* b1    = (const float*)d_in[4];
    const float* beta2 = (const float*)d_in[5];
    const float* W2    = (const float*)d_in[6];
    const float* b2    = (const float*)d_in[7];
    const float* W3    = (const float*)d_in[8];
    const float* b3    = (const float*)d_in[9];
    float* out = (float*)d_out;

    const int N = in_sizes[2];          // 30000
    const int E = in_sizes[1] / 2;      // 480000
    const int F_IN = in_sizes[0] / N;   // 1280
    const int H = in_sizes[4];          // 512
    const int H2 = in_sizes[7];         // 256
    const int C = in_sizes[9];          // 10
    const int G = out_size / C;         // 64

    char* ws = (char*)d_ws;
    unsigned short* H1B = (unsigned short*)(ws + 0);            // 30.72 MB bf16
    unsigned short* HPB = (unsigned short*)(ws + 31000000L);    // 30.72 MB bf16
    unsigned short* H2B = (unsigned short*)(ws + 62000000L);    // 30.72 MB bf16
    float*          H3  = (float*)(ws + 0);                     // 61.44 MB f32 (over H1B/HPB, both dead)
    unsigned short* W1T = (unsigned short*)(ws + 93000000L);    // 1.31 MB
    unsigned short* W2T = (unsigned short*)(ws + 94500000L);    // 0.26 MB
    float* INVN_A = (float*)(ws + 95000000L);                   // 120 KB
    float* INVN_B = (float*)(ws + 95200000L);                   // 120 KB
    int*   CNT    = (int*)(ws + 95400000L);
    int*   FILL   = (int*)(ws + 95600000L);
    int*   ROWP   = (int*)(ws + 95800000L);
    int*   COL    = (int*)(ws + 96000000L);                     // 2.04 MB
    int*   BSUM   = (int*)(ws + 98100000L);
    int*   START  = (int*)(ws + 98110000L);
    float* POOLED = (float*)(ws + 98120000L);                   // 131 KB

    // 1. weight transposes (f32 -> bf16 [N][K])
    { dim3 g1(F_IN / 32, H / 32); k_transpose_bf16<<<g1, 256, 0, stream>>>(W1, W1T, F_IN, H); }
    { dim3 g2(H / 32, H2 / 32);   k_transpose_bf16<<<g2, 256, 0, stream>>>(W2, W2T, H, H2); }

    // 2. CSR (incoming edges + self loops)
    int nb = (N + 1023) / 1024;   // 30
    k_csr_init<<<(N + 255) / 256, 256, 0, stream>>>(CNT, FILL, N);
    k_csr_count<<<(E + 255) / 256, 256, 0, stream>>>(ei, CNT, E);
    k_scan1<<<nb, 1024, 0, stream>>>(CNT, ROWP, BSUM, N);
    k_scan2<<<1, 64, 0, stream>>>(BSUM, nb);
    k_scan3<<<(N + 1 + 1023) / 1024, 1024, 0, stream>>>(BSUM, ROWP, N, nb);
    k_csr_fill<<<(E + N + 255) / 256, 256, 0, stream>>>(ei, ROWP, FILL, COL, E, N);

    // 3. GEMM1: H1B = bf16(relu(x @ W1 + b1))  [N,512]; 128x256 tiles
    {
        dim3 grid((N + 127) / 128, H / 256);
        k_gemm_bias_relu<1280, 256, 512, true, true>
            <<<grid, 512, 0, stream>>>(x, W1T, b1, H1B, N);
    }

    // 4. prop1 (beta=1): HPB = AGNN(H1B), fused invn of HPB -> INVN_B
    k_norm_bf16<<<(N + 3) / 4, 256, 0, stream>>>(H1B, INVN_A, N);
    k_agnn<<<(N + 3) / 4, 256, 0, stream>>>(H1B, INVN_A, ROWP, COL, nullptr, HPB, INVN_B, N);

    // 5. prop2 (beta=beta2): H2B = AGNN(HPB)
    k_agnn<<<(N + 3) / 4, 256, 0, stream>>>(HPB, INVN_B, ROWP, COL, beta2, H2B, nullptr, N);

    // 6. GEMM2: H3 = relu(H2B @ W2 + b2)  [N,256] f32; BN=256 read-once A
    {
        dim3 grid((N + 127) / 128, 1);
        k_gemm_bias_relu<512, 256, 256, false, false>
            <<<grid, 512, 0, stream>>>(H2B, W2T, b2, H3, N);
    }

    // 7. pool + final linear
    k_bounds<<<1, 128, 0, stream>>>(batch, START, N, G);
    k_pool<<<G, 256, 0, stream>>>(H3, START, POOLED);
    k_final<<<G, 64, 0, stream>>>(POOLED, W3, b3, out, C);
}

// Round 7
// 375.339 us; speedup vs baseline: 3.5111x; 1.0022x over previous
//
#include <hip/hip_runtime.h>
#include <hip/hip_bf16.h>
#include <cstdint>

// ---------------------------------------------------------------------------
// Model: h=relu(x@W1+b1); h=AGNN(h,beta=1); h=AGNN(h,beta2); h=relu(h@W2+b2);
//        out = concat(segmax(h,batch), segmean(h,batch)) @ W3 + b3
// N=30000, E=480000, F_IN=1280, H=512, H2=256, G=64, C=10
// bf16 rows through propagation; 128x256 8-wave MFMA GEMMs with depth-2
// triple-buffered pipeline (raw s_barrier + counted vmcnt, T3/T4);
// XOR-swizzled LDS; DPP wave reduction in AGNN.
// ---------------------------------------------------------------------------

typedef __attribute__((ext_vector_type(8))) short bf16x8;
typedef __attribute__((ext_vector_type(4))) float f32x4;
typedef __attribute__((ext_vector_type(8))) unsigned short ushort8;
typedef __attribute__((ext_vector_type(4))) unsigned short ushort4v;
typedef __attribute__((ext_vector_type(4))) unsigned int uint4v;

#define WAITV(n) asm volatile("s_waitcnt vmcnt(" #n ")" ::: "memory")
#define WAITLGKM asm volatile("s_waitcnt lgkmcnt(0)" ::: "memory")

__device__ inline unsigned short f2bf(float f) {
    unsigned int u = __float_as_uint(f);
    u += 0x7FFFu + ((u >> 16) & 1u);   // RNE
    return (unsigned short)(u >> 16);
}

__device__ __forceinline__ float bf2f(unsigned short u) {
    return __uint_as_float(((unsigned int)u) << 16);
}

// packed f32x2 -> bf16x2 (RNE), single HW instruction on gfx950
__device__ __forceinline__ unsigned int cvtpk(float lo, float hi) {
    unsigned int r;
    asm("v_cvt_pk_bf16_f32 %0, %1, %2" : "=v"(r) : "v"(lo), "v"(hi));
    return r;
}

__device__ __forceinline__ void gload_lds16(const void* g, void* l) {
    __builtin_amdgcn_global_load_lds(
        (const __attribute__((address_space(1))) void*)g,
        (__attribute__((address_space(3))) void*)l, 16, 0, 0);
}

// ---- wave64 sum via DPP (VALU pipe, no ds_bpermute). Result uniform. ------
__device__ __forceinline__ float wave_sum_dpp(float p) {
    int t;
    t = __builtin_amdgcn_update_dpp(0, __float_as_int(p), 0xB1, 0xf, 0xf, true);  // quad_perm [1,0,3,2]
    p += __int_as_float(t);
    t = __builtin_amdgcn_update_dpp(0, __float_as_int(p), 0x4E, 0xf, 0xf, true);  // quad_perm [2,3,0,1]
    p += __int_as_float(t);
    t = __builtin_amdgcn_update_dpp(0, __float_as_int(p), 0x141, 0xf, 0xf, true); // row_half_mirror
    p += __int_as_float(t);
    t = __builtin_amdgcn_update_dpp(0, __float_as_int(p), 0x140, 0xf, 0xf, true); // row_mirror
    p += __int_as_float(t);
    t = __builtin_amdgcn_update_dpp(0, __float_as_int(p), 0x142, 0xf, 0xf, true); // row_bcast15
    p += __int_as_float(t);
    t = __builtin_amdgcn_update_dpp(0, __float_as_int(p), 0x143, 0xf, 0xf, true); // row_bcast31
    p += __int_as_float(t);
    return __int_as_float(__builtin_amdgcn_readlane(__float_as_int(p), 63));
}

// ---- tiled transpose: W [K][N] f32 -> Wt [N][K] bf16 (K,N multiples of 32) -
__global__ __launch_bounds__(256) void k_transpose_bf16(
    const float* __restrict__ W, unsigned short* __restrict__ Wt, int K, int N) {
    __shared__ unsigned short t[32][33];
    int k0 = blockIdx.x * 32, n0 = blockIdx.y * 32;
    int tr = threadIdx.x >> 3;          // 0..31
    int tc = (threadIdx.x & 7) * 4;     // 0,4,...,28
    float4 v = *(const float4*)(W + (long)(k0 + tr) * N + n0 + tc);
    t[tr][tc + 0] = f2bf(v.x); t[tr][tc + 1] = f2bf(v.y);
    t[tr][tc + 2] = f2bf(v.z); t[tr][tc + 3] = f2bf(v.w);
    __syncthreads();
    ushort4v o = { t[tc + 0][tr], t[tc + 1][tr], t[tc + 2][tr], t[tc + 3][tr] };
    *(ushort4v*)(Wt + (long)(n0 + tr) * K + k0 + tc) = o;
}

// ---- MFMA GEMM: C[M][N] = relu(A[M][K] @ Bt[N][K]^T + bias) ---------------
// Block tile 128 x BN (BN=256), 512 threads = 8 waves (2m x 4n), wave tile
// 64x64 (acc[4][4]), BK=32. Triple-buffered LDS (72 KB), depth-2 prefetch:
// tile t+2 loads issued right after barrier(t); tile t awaited with COUNTED
// vmcnt (6 ops of t+1/t+2 stay in flight across barriers -> HBM/L3 latency
// hidden under 2 full K-steps of MFMA). Raw s_barrier (no vmcnt(0) drain).
// ds_write visibility: DS ops retire in order, MFMA operand lgkm waits force
// the (older) ds_write complete before any wave reaches the next barrier.
// LDS rows 64B; 16B granule g of row r at slot g ^ ((r>>1)&3) (conflict-free,
// both sides: pre-swizzled global source / swizzled ds addrs).
// AF32: A f32 in global, reg-staged + packed to bf16 (swizzled ds_write).
template <int K, int BN, int NOUT, bool AF32, bool OUTBF16>
__global__ __launch_bounds__(512, 4) void k_gemm_bias_relu(
    const void* __restrict__ Av, const unsigned short* __restrict__ Bt,
    const float* __restrict__ bias, void* __restrict__ Cv, int M) {
    constexpr int NS = K / 32;
    __shared__ unsigned short As[3][128 * 32];
    __shared__ unsigned short Bs[3][BN * 32];
    int tid = threadIdx.x;
    int w = tid >> 6, l = tid & 63;
    int wm = w >> 2, wn = w & 3;
    int mBase = blockIdx.x * 128;
    int nBase = blockIdx.y * BN;

    const float* Af = (const float*)Av;
    const unsigned short* Ab = (const unsigned short*)Av;

    // AF32 reg-staging: thread owns 8 consecutive f32 of one row (4 thr/row)
    int arow = tid >> 2;                          // 0..127
    int aslot = (tid & 3) ^ ((arow >> 1) & 3);    // swizzled 16B slot
    long aRowG = mBase + arow; if (aRowG >= M) aRowG = M - 1;
    const float* aptr = AF32 ? (Af + aRowG * K + (tid & 3) * 8) : nullptr;

    auto stageB = [&](int b, int k0) {
#pragma unroll
        for (int o = 0; o < BN / 128; ++o) {
            int rbase = (w * (BN / 128) + o) * 16;       // wave-uniform
            int row = rbase + (l >> 2);                  // local B row
            int gsrc = (l & 3) ^ ((row >> 1) & 3);       // pre-swizzled src
            gload_lds16(Bt + (long)(nBase + row) * K + k0 + gsrc * 8,
                        &Bs[b][rbase * 32]);
        }
    };
    auto stageAbf = [&](int b, int k0) {
        int rbase = w * 16;
        int row = rbase + (l >> 2);
        int gsrc = (l & 3) ^ ((row >> 1) & 3);
        long gr = mBase + row; if (gr >= M) gr = M - 1;
        gload_lds16(Ab + gr * K + k0 + gsrc * 8, &As[b][rbase * 32]);
    };
    auto loadA = [&](int k0, float4& u0, float4& u1) {
        u0 = *(const float4*)(aptr + k0);
        u1 = *(const float4*)(aptr + k0 + 4);
    };
    auto writeA = [&](int b, float4 u0, float4 u1) {
        uint4v p = { cvtpk(u0.x, u0.y), cvtpk(u0.z, u0.w),
                     cvtpk(u1.x, u1.y), cvtpk(u1.z, u1.w) };
        *(uint4v*)(&As[b][arow * 32 + aslot * 8]) = p;
    };

    f32x4 acc[4][4] = {};
    float4 curA0 = {}, curA1 = {}, nxtA0 = {}, nxtA1 = {};

    // ---- prologue: tiles 0 and 1 in flight --------------------------------
    if constexpr (AF32) {
        float4 z0, z1;
        loadA(0, z0, z1);           // f32 tile0 (oldest vmem ops)
        stageB(0, 0);
        loadA(32, curA0, curA1);    // f32 tile1
        stageB(1, 32);
        writeA(0, z0, z1);          // auto-waits f32 tile0 only (oldest)
    } else {
        stageAbf(0, 0); stageB(0, 0);
        stageAbf(1, 32); stageB(1, 32);
    }
    WAITLGKM;                        // ds_write(0) visible before barrier

#pragma unroll
    for (int t = 0; t < NS; ++t) {
        const int cb = t % 3, nb = (t + 1) % 3, fb = (t + 2) % 3;
        __builtin_amdgcn_s_barrier();        // raw: no vmcnt drain
        __builtin_amdgcn_sched_barrier(0);
        if constexpr (AF32) {
            if (t + 2 < NS) {
                loadA((t + 2) * 32, nxtA0, nxtA1);   // f32(t+2) before gB(t+2)
                stageB(fb, (t + 2) * 32);
            }
            if (t + 1 < NS) {
                writeA(nb, curA0, curA1);            // auto-waits f32(t+1)
                curA0 = nxtA0; curA1 = nxtA1;
            }
            if (t < NS - 2) { WAITV(6); }            // tile t fully landed;
            else if (t == NS - 2) { WAITV(2); }      // t+1/t+2 stay in flight
            else { WAITV(0); }
        } else {
            if (t + 2 < NS) {
                stageAbf(fb, (t + 2) * 32);          // group: [gA, gB, gB]
                stageB(fb, (t + 2) * 32);
            }
            if (t < NS - 2) { WAITV(6); }
            else if (t == NS - 2) { WAITV(3); }
            else { WAITV(0); }
        }
        __builtin_amdgcn_sched_barrier(0);
        // ---- compute tile t from buffer cb (swizzled reads) ---------------
        bf16x8 af[4];
#pragma unroll
        for (int m = 0; m < 4; ++m) {
            int ra = wm * 64 + m * 16 + (l & 15);
            int g = (l >> 4) ^ ((ra >> 1) & 3);
            af[m] = *(const bf16x8*)(&As[cb][ra * 32 + g * 8]);
        }
#pragma unroll
        for (int n = 0; n < 4; ++n) {
            int rb = wn * 64 + n * 16 + (l & 15);
            int g = (l >> 4) ^ ((rb >> 1) & 3);
            bf16x8 bfr = *(const bf16x8*)(&Bs[cb][rb * 32 + g * 8]);
#pragma unroll
            for (int m = 0; m < 4; ++m)
                acc[m][n] = __builtin_amdgcn_mfma_f32_16x16x32_bf16(
                    af[m], bfr, acc[m][n], 0, 0, 0);
        }
    }

    // ---- epilogue: row=(l>>4)*4+r, col=l&15 (HW-verified) -----------------
#pragma unroll
    for (int m = 0; m < 4; ++m) {
        int row = mBase + wm * 64 + m * 16 + (l >> 4) * 4;
#pragma unroll
        for (int n = 0; n < 4; ++n) {
            int colg = nBase + wn * 64 + n * 16 + (l & 15);
            float bv = bias[colg];
#pragma unroll
            for (int r = 0; r < 4; ++r) {
                if (row + r < M) {
                    float v = fmaxf(acc[m][n][r] + bv, 0.f);
                    if constexpr (OUTBF16)
                        ((unsigned short*)Cv)[(long)(row + r) * NOUT + colg] = f2bf(v);
                    else
                        ((float*)Cv)[(long)(row + r) * NOUT + colg] = v;
                }
            }
        }
    }
}

// ---- CSR build ------------------------------------------------------------
__global__ void k_csr_init(int* __restrict__ cnt, int* __restrict__ fill, int n) {
    int i = blockIdx.x * blockDim.x + threadIdx.x;
    if (i < n) { cnt[i] = 1; fill[i] = 0; }   // 1 = self loop
}

__global__ void k_csr_count(const int* __restrict__ ei, int* __restrict__ cnt, int E) {
    int e = blockIdx.x * blockDim.x + threadIdx.x;
    if (e < E) atomicAdd(&cnt[ei[E + e]], 1);   // dst row
}

// hierarchical exclusive scan: phase 1 (per-1024-chunk scan + chunk total)
__global__ __launch_bounds__(1024) void k_scan1(const int* __restrict__ cnt,
                                                int* __restrict__ rowp,
                                                int* __restrict__ bsum, int n) {
    __shared__ int wsum[16];
    int b = blockIdx.x, t = threadIdx.x, lane = t & 63, w = t >> 6;
    int i = b * 1024 + t;
    int v = (i < n) ? cnt[i] : 0;
    int x = v;
#pragma unroll
    for (int off = 1; off < 64; off <<= 1) {
        int y = __shfl_up(x, off, 64);
        if (lane >= off) x += y;
    }
    if (lane == 63) wsum[w] = x;
    __syncthreads();
    if (t < 16) {
        int s = wsum[t];
#pragma unroll
        for (int off = 1; off < 16; off <<= 1) {
            int y = __shfl_up(s, off, 64);
            if (t >= off) s += y;
        }
        wsum[t] = s;
    }
    __syncthreads();
    int wo = w ? wsum[w - 1] : 0;
    if (i < n) rowp[i] = wo + x - v;            // chunk-local exclusive
    if (t == 0) bsum[b] = wsum[15];             // chunk total
}

// phase 2: exclusive scan of <=64 chunk totals (single wave)
__global__ __launch_bounds__(64) void k_scan2(int* __restrict__ bsum, int nb) {
    int lane = threadIdx.x;
    int v = (lane < nb) ? bsum[lane] : 0;
    int x = v;
#pragma unroll
    for (int off = 1; off < 64; off <<= 1) {
        int y = __shfl_up(x, off, 64);
        if (lane >= off) x += y;
    }
    int total = __shfl(x, nb - 1, 64);
    if (lane < nb) bsum[lane] = x - v;          // exclusive
    if (lane == 0) bsum[nb] = total;
}

// phase 3: add chunk offsets; write rowp[n] = total
__global__ __launch_bounds__(1024) void k_scan3(const int* __restrict__ bsum,
                                                int* __restrict__ rowp, int n, int nb) {
    int i = blockIdx.x * 1024 + threadIdx.x;
    if (i < n) rowp[i] += bsum[i >> 10];
    else if (i == n) rowp[n] = bsum[nb];
}

__global__ void k_csr_fill(const int* __restrict__ ei, const int* __restrict__ rowp,
                           int* __restrict__ fill, int* __restrict__ col, int E, int n) {
    int idx = blockIdx.x * blockDim.x + threadIdx.x;
    if (idx < E) {
        int d = ei[E + idx];
        int s = ei[idx];
        int pos = atomicAdd(&fill[d], 1);
        col[rowp[d] + pos] = s;
    } else if (idx < E + n) {
        int nd = idx - E;
        int pos = atomicAdd(&fill[nd], 1);
        col[rowp[nd] + pos] = nd;   // self loop
    }
}

// ---- row inverse L2 norm, bf16 rows (H=512) --------------------------------
__global__ __launch_bounds__(256) void k_norm_bf16(const unsigned short* __restrict__ h,
                                                   float* __restrict__ invn, int n) {
    int row = blockIdx.x * 4 + (threadIdx.x >> 6);
    int lane = threadIdx.x & 63;
    if (row >= n) return;
    ushort8 v = *(const ushort8*)(h + (long)row * 512 + lane * 8);
    float s = 0.f;
#pragma unroll
    for (int e = 0; e < 8; ++e) { float f = bf2f(v[e]); s += f * f; }
    s = wave_sum_dpp(s);
    if (lane == 0) invn[row] = 1.f / fmaxf(sqrtf(s), 1e-12f);
}

// ---- AGNN propagation: bf16 rows, one wave per dst, single-pass -----------
// DPP wave reduce (no ds_bpermute in the per-edge chain); readlane broadcasts.
// Optionally fuses the inv-L2-norm of the OUTPUT row (for the next prop).
__global__ __launch_bounds__(256) void k_agnn(
    const unsigned short* __restrict__ h, const float* __restrict__ invn,
    const int* __restrict__ rowp, const int* __restrict__ col,
    const float* __restrict__ beta_ptr, unsigned short* __restrict__ out,
    float* __restrict__ invn_out, int nNodes) {
    int dst = blockIdx.x * 4 + (threadIdx.x >> 6);
    int lane = threadIdx.x & 63;
    if (dst >= nNodes) return;
    float beta = beta_ptr ? beta_ptr[0] : 1.0f;
    ushort8 hdv = *(const ushort8*)(h + (long)dst * 512 + lane * 8);
    float hd[8];
#pragma unroll
    for (int e = 0; e < 8; ++e) hd[e] = bf2f(hdv[e]);
    float coef = beta * invn[dst];
    int s0 = rowp[dst], s1 = rowp[dst + 1];

    float m = -1e30f, ssum = 0.f;
    float acc[8] = {0.f, 0.f, 0.f, 0.f, 0.f, 0.f, 0.f, 0.f};

    for (int base = s0; base < s1; base += 64) {
        int cnt = min(s1 - base, 64);
        int gi = base + lane; if (gi >= s1) gi = s1 - 1;
        int idxl = col[gi];              // batch of up to 64 edge indices
        float vinl = invn[idxl];         // batch of src inv-norms
        int src0 = __builtin_amdgcn_readlane(idxl, 0);
        ushort8 nxt = *(const ushort8*)(h + (long)src0 * 512 + lane * 8);
        for (int j = 0; j < cnt; ++j) {
            ushort8 cur = nxt;
            if (j + 1 < cnt) {
                int sn = __builtin_amdgcn_readlane(idxl, j + 1);
                nxt = *(const ushort8*)(h + (long)sn * 512 + lane * 8);  // prefetch
            }
            float a[8];
#pragma unroll
            for (int e = 0; e < 8; ++e) a[e] = bf2f(cur[e]);
            float p = a[0] * hd[0] + a[1] * hd[1] + a[2] * hd[2] + a[3] * hd[3] +
                      a[4] * hd[4] + a[5] * hd[5] + a[6] * hd[6] + a[7] * hd[7];
            p = wave_sum_dpp(p);         // uniform across wave
            float vin_j = __int_as_float(
                __builtin_amdgcn_readlane(__float_as_int(vinl), j));
            float alpha = coef * vin_j * p;
            if (alpha > m) {             // wave-uniform
                float sc = __expf(m - alpha);
                ssum *= sc;
#pragma unroll
                for (int e = 0; e < 8; ++e) acc[e] *= sc;
                m = alpha;
            }
            float wgt = __expf(alpha - m);
            ssum += wgt;
#pragma unroll
            for (int e = 0; e < 8; ++e) acc[e] += wgt * a[e];
        }
    }
    float inv_s = 1.f / ssum;
#pragma unroll
    for (int e = 0; e < 8; ++e) acc[e] *= inv_s;

    uint4v o = { cvtpk(acc[0], acc[1]), cvtpk(acc[2], acc[3]),
                 cvtpk(acc[4], acc[5]), cvtpk(acc[6], acc[7]) };
    *(uint4v*)(out + (long)dst * 512 + lane * 8) = o;

    if (invn_out) {                      // fused output norm (feeds next prop)
        float s = 0.f;
#pragma unroll
        for (int e = 0; e < 8; ++e) s += acc[e] * acc[e];
        s = wave_sum_dpp(s);
        if (lane == 0) invn_out[dst] = 1.f / fmaxf(sqrtf(s), 1e-12f);
    }
}

// ---- graph boundaries in sorted batch -------------------------------------
__global__ void k_bounds(const int* __restrict__ batch, int* __restrict__ starts,
                         int n, int G) {
    int g = blockIdx.x * blockDim.x + threadIdx.x;
    if (g > G) return;
    int lo = 0, hi = n;
    while (lo < hi) {
        int mid = (lo + hi) >> 1;
        if (batch[mid] < g) lo = mid + 1; else hi = mid;
    }
    starts[g] = lo;
}

// ---- per-graph max/mean pool (H2=256) -------------------------------------
__global__ __launch_bounds__(256) void k_pool(const float* __restrict__ h3,
                                              const int* __restrict__ starts,
                                              float* __restrict__ pooled) {
    int g = blockIdx.x;
    int t = threadIdx.x;
    int s = starts[g], e = starts[g + 1];
    float mx = -3.402823466e38f, sm = 0.f;
    int r = s;
    for (; r + 4 <= e; r += 4) {          // ILP unroll
        float v0 = h3[(long)(r + 0) * 256 + t];
        float v1 = h3[(long)(r + 1) * 256 + t];
        float v2 = h3[(long)(r + 2) * 256 + t];
        float v3 = h3[(long)(r + 3) * 256 + t];
        mx = fmaxf(mx, fmaxf(fmaxf(v0, v1), fmaxf(v2, v3)));
        sm += (v0 + v1) + (v2 + v3);
    }
    for (; r < e; ++r) {
        float v = h3[(long)r * 256 + t];
        mx = fmaxf(mx, v); sm += v;
    }
    float cnt = fmaxf((float)(e - s), 1.f);
    pooled[g * 512 + t] = mx;
    pooled[g * 512 + 256 + t] = sm / cnt;
}

// ---- final tiny GEMM: out[G][C] = pooled[G][512] @ W3[512][C] + b3 --------
__global__ __launch_bounds__(64) void k_final(const float* __restrict__ pooled,
                                              const float* __restrict__ W3,
                                              const float* __restrict__ b3,
                                              float* __restrict__ out, int C) {
    int g = blockIdx.x;
    int lane = threadIdx.x;
    for (int c = 0; c < C; c++) {
        float p = 0.f;
        for (int k = lane; k < 512; k += 64) p += pooled[g * 512 + k] * W3[k * C + c];
#pragma unroll
        for (int off = 32; off; off >>= 1) p += __shfl_xor(p, off, 64);
        if (lane == 0) out[g * C + c] = p + b3[c];
    }
}

// ---------------------------------------------------------------------------
extern "C" void kernel_launch(void* const* d_in, const int* in_sizes, int n_in,
                              void* d_out, int out_size, void* d_ws, size_t ws_size,
                              hipStream_t stream) {
    const float* x     = (const float*)d_in[0];
    const int*   ei    = (const int*)d_in[1];
    const int*   batch = (const int*)d_in[2];
    const float* W1    = (const float*)d_in[3];
    const float* b1    = (const float*)d_in[4];
    const float* beta2 = (const float*)d_in[5];
    const float* W2    = (const float*)d_in[6];
    const float* b2    = (const float*)d_in[7];
    const float* W3    = (const float*)d_in[8];
    const float* b3    = (const float*)d_in[9];
    float* out = (float*)d_out;

    const int N = in_sizes[2];          // 30000
    const int E = in_sizes[1] / 2;      // 480000
    const int F_IN = in_sizes[0] / N;   // 1280
    const int H = in_sizes[4];          // 512
    const int H2 = in_sizes[7];         // 256
    const int C = in_sizes[9];          // 10
    const int G = out_size / C;         // 64

    char* ws = (char*)d_ws;
    unsigned short* H1B = (unsigned short*)(ws + 0);            // 30.72 MB bf16
    unsigned short* HPB = (unsigned short*)(ws + 31000000L);    // 30.72 MB bf16
    unsigned short* H2B = (unsigned short*)(ws + 62000000L);    // 30.72 MB bf16
    float*          H3  = (float*)(ws + 0);                     // 61.44 MB f32 (over H1B/HPB, both dead)
    unsigned short* W1T = (unsigned short*)(ws + 93000000L);    // 1.31 MB
    unsigned short* W2T = (unsigned short*)(ws + 94500000L);    // 0.26 MB
    float* INVN_A = (float*)(ws + 95000000L);                   // 120 KB
    float* INVN_B = (float*)(ws + 95200000L);                   // 120 KB
    int*   CNT    = (int*)(ws + 95400000L);
    int*   FILL   = (int*)(ws + 95600000L);
    int*   ROWP   = (int*)(ws + 95800000L);
    int*   COL    = (int*)(ws + 96000000L);                     // 2.04 MB
    int*   BSUM   = (int*)(ws + 98100000L);
    int*   START  = (int*)(ws + 98110000L);
    float* POOLED = (float*)(ws + 98120000L);                   // 131 KB

    // 1. weight transposes (f32 -> bf16 [N][K])
    { dim3 g1(F_IN / 32, H / 32); k_transpose_bf16<<<g1, 256, 0, stream>>>(W1, W1T, F_IN, H); }
    { dim3 g2(H / 32, H2 / 32);   k_transpose_bf16<<<g2, 256, 0, stream>>>(W2, W2T, H, H2); }

    // 2. CSR (incoming edges + self loops)
    int nb = (N + 1023) / 1024;   // 30
    k_csr_init<<<(N + 255) / 256, 256, 0, stream>>>(CNT, FILL, N);
    k_csr_count<<<(E + 255) / 256, 256, 0, stream>>>(ei, CNT, E);
    k_scan1<<<nb, 1024, 0, stream>>>(CNT, ROWP, BSUM, N);
    k_scan2<<<1, 64, 0, stream>>>(BSUM, nb);
    k_scan3<<<(N + 1 + 1023) / 1024, 1024, 0, stream>>>(BSUM, ROWP, N, nb);
    k_csr_fill<<<(E + N + 255) / 256, 256, 0, stream>>>(ei, ROWP, FILL, COL, E, N);

    // 3. GEMM1: H1B = bf16(relu(x @ W1 + b1))  [N,512]; 128x256 tiles
    {
        dim3 grid((N + 127) / 128, H / 256);
        k_gemm_bias_relu<1280, 256, 512, true, true>
            <<<grid, 512, 0, stream>>>(x, W1T, b1, H1B, N);
    }

    // 4. prop1 (beta=1): HPB = AGNN(H1B), fused invn of HPB -> INVN_B
    k_norm_bf16<<<(N + 3) / 4, 256, 0, stream>>>(H1B, INVN_A, N);
    k_agnn<<<(N + 3) / 4, 256, 0, stream>>>(H1B, INVN_A, ROWP, COL, nullptr, HPB, INVN_B, N);

    // 5. prop2 (beta=beta2): H2B = AGNN(HPB)
    k_agnn<<<(N + 3) / 4, 256, 0, stream>>>(HPB, INVN_B, ROWP, COL, beta2, H2B, nullptr, N);

    // 6. GEMM2: H3 = relu(H2B @ W2 + b2)  [N,256] f32; BN=256 read-once A
    {
        dim3 grid((N + 127) / 128, 1);
        k_gemm_bias_relu<512, 256, 256, false, false>
            <<<grid, 512, 0, stream>>>(H2B, W2T, b2, H3, N);
    }

    // 7. pool + final linear
    k_bounds<<<1, 128, 0, stream>>>(batch, START, N, G);
    k_pool<<<G, 256, 0, stream>>>(H3, START, POOLED);
    k_final<<<G, 64, 0, stream>>>(POOLED, W3, b3, out, C);
}